// Round 6
// baseline (1010.985 us; speedup 1.0000x reference)
//
#include <hip/hip_runtime.h>
#include <hip/hip_bf16.h>

typedef __attribute__((ext_vector_type(8))) short s8v;
typedef __attribute__((ext_vector_type(4))) float f4v;
typedef unsigned short ushort;
typedef unsigned int uint;

union V8 { s8v v; short s[8]; };

__device__ __forceinline__ short f2bf(float v){
    union { __hip_bfloat16 b; short u; } x;
    x.b = __float2bfloat16(v);
    return x.u;
}
__device__ __forceinline__ float bf2f(short u){
    union { short u; __hip_bfloat16 b; } x;
    x.u = u;
    return __bfloat162float(x.b);
}
__device__ __forceinline__ void splitf(float v, short& h, short& l){
    h = f2bf(v);
    l = f2bf(v - bf2f(h));
}

// async global->LDS, 16B per lane. LDS dest is wave-uniform base + lane*16
// (m104); global src is per-lane.
__device__ __forceinline__ void gl_lds16(const void* g, void* l){
    __builtin_amdgcn_global_load_lds(
        (const __attribute__((address_space(1))) void*)g,
        (__attribute__((address_space(3))) void*)l, 16, 0, 0);
}

// ---------------------------------------------------------------------------
// conv1 (CIN=3): direct conv + pool + ReLU -> NHWC hi/lo bf16 planes.
// ---------------------------------------------------------------------------
template<int CIN, int HIN, int PH, int OCB, int SPT, int CICH, int COUT>
__global__ __launch_bounds__(SPT) void k_conv_pool_relu(
    const float* __restrict__ in, const float* __restrict__ w,
    const float* __restrict__ bias, ushort* __restrict__ outh,
    ushort* __restrict__ outl)
{
    constexpr int WIN   = HIN;
    constexpr int PW    = PH;
    constexpr int WSTR  = CICH * 9 + 1;

    __shared__ float wsh[OCB * WSTR];

    const int b   = blockIdx.z;
    const int oc0 = blockIdx.y * OCB;
    const int t   = threadIdx.x;
    const int sp  = blockIdx.x * SPT + t;
    const bool active = sp < PH * PW;
    const int py = active ? (sp / PW) : 0;
    const int px = active ? (sp % PW) : 0;

    float acc[OCB][4];
#pragma unroll
    for (int j = 0; j < OCB; ++j)
        acc[j][0] = acc[j][1] = acc[j][2] = acc[j][3] = 0.f;

    const float* inb = in + (size_t)b * CIN * HIN * WIN;

    for (int c0 = 0; c0 < CIN; c0 += CICH) {
        __syncthreads();
        for (int i = t; i < OCB * CICH * 9; i += SPT) {
            int j = i / (CICH * 9);
            int r = i - j * (CICH * 9);
            wsh[j * WSTR + r] = w[((size_t)(oc0 + j) * CIN + c0) * 9 + r];
        }
        __syncthreads();

        for (int ci = 0; ci < CICH; ++ci) {
            const float* inc = inb + (size_t)(c0 + ci) * HIN * WIN
                             + (2 * py) * WIN + 2 * px;
            float patch[4][4];
#pragma unroll
            for (int r = 0; r < 4; ++r)
#pragma unroll
                for (int c = 0; c < 4; ++c)
                    patch[r][c] = inc[r * WIN + c];

#pragma unroll
            for (int j = 0; j < OCB; ++j) {
                const float* wp = &wsh[j * WSTR + ci * 9];
#pragma unroll
                for (int kh = 0; kh < 3; ++kh)
#pragma unroll
                    for (int kw = 0; kw < 3; ++kw) {
                        float wv = wp[kh * 3 + kw];
                        acc[j][0] = fmaf(patch[kh][kw],         wv, acc[j][0]);
                        acc[j][1] = fmaf(patch[kh][kw + 1],     wv, acc[j][1]);
                        acc[j][2] = fmaf(patch[kh + 1][kw],     wv, acc[j][2]);
                        acc[j][3] = fmaf(patch[kh + 1][kw + 1], wv, acc[j][3]);
                    }
            }
        }
    }

    if (active) {
        union { ushort us[OCB]; uint4 u4[OCB / 8]; } TH, TL;
#pragma unroll
        for (int j = 0; j < OCB; ++j) {
            float m = fmaxf(fmaxf(acc[j][0], acc[j][1]),
                            fmaxf(acc[j][2], acc[j][3]));
            m = fmaxf(m + bias[oc0 + j], 0.f);
            short h, l; splitf(m, h, l);
            TH.us[j] = (ushort)h; TL.us[j] = (ushort)l;
        }
        size_t base = ((size_t)b * PH * PW + sp) * COUT + oc0;
#pragma unroll
        for (int q = 0; q < OCB / 8; ++q) {
            ((uint4*)(outh + base))[q] = TH.u4[q];
            ((uint4*)(outl + base))[q] = TL.u4[q];
        }
    }
}

// ---------------------------------------------------------------------------
// Conv weight split WITH K-permutation: w[n][ci*9+r] -> planes [n][r*CIN+ci].
// ---------------------------------------------------------------------------
__global__ void k_wsplit_perm(const float* __restrict__ w, ushort* __restrict__ oh,
                              ushort* __restrict__ ol, int CIN, int total)
{
    int i = blockIdx.x * 256 + threadIdx.x;
    if (i < total) {
        int K = CIN * 9;
        int n = i / K;
        int rem = i - n * K;
        int ci = rem / 9;
        int r = rem - 9 * ci;
        short h, l; splitf(w[i], h, l);
        size_t o = (size_t)n * K + r * CIN + ci;
        oh[o] = (ushort)h; ol[o] = (ushort)l;
    }
}

// Transpose+split: f32 [K][N] -> hi/lo ushort planes [n][k]. 32x32 tiles.
__global__ __launch_bounds__(256) void k_wsplitT(
    const float* __restrict__ B, ushort* __restrict__ oh, ushort* __restrict__ ol,
    int K, int N)
{
    __shared__ float tl[32][33];
    const int n0 = blockIdx.x * 32, k0 = blockIdx.y * 32;
    const int r = threadIdx.x >> 5, c = threadIdx.x & 31;
#pragma unroll
    for (int it = 0; it < 4; ++it) {
        int row = r + it * 8;
        tl[row][c] = B[(size_t)(k0 + row) * N + n0 + c];
    }
    __syncthreads();
#pragma unroll
    for (int it = 0; it < 4; ++it) {
        int a = r + it * 8;
        float v = tl[c][a];
        short h, l; splitf(v, h, l);
        size_t o = (size_t)(n0 + a) * K + k0 + c;
        oh[o] = (ushort)h; ol[o] = (ushort)l;
    }
}

// ---------------------------------------------------------------------------
// Split-bf16 MFMA GEMM v9: double-buffered gl_lds with cross-step prefetch
// (T3/T4 minimum 2-phase recipe). Per K-step: issue NEXT tile's async loads
// into buf^1, then ds_read+MFMA on buf, then ONE __syncthreads() (vmcnt(0)
// covers the prefetch, lgkmcnt the ds ops) -> load latency hides under MFMA.
// MT=128: tile 128x128, 4 waves, wave = 64x64 (4x4), 48 MFMA/K-step.
// MT=64 : tile 64x128, wave = 32x64 (2x4).
// MODE 0: implicit-GEMM conv, in-register 2x2 maxpool + bias + ReLU epilogue.
//   EPI 0: NHWC hi/lo planes out; EPI 1: NCHW hi/lo planes out (FC1 A layout).
// MODE 1: FC partial (grid.z K-split), f32 partials out.
// ---------------------------------------------------------------------------
template<int MODE, int BPRE, int EPI, int LOG2CIN, int K, int KCH, int N,
         int HIN, int PPH, int PPW, int COUT, int TPI, int MT>
__global__ __launch_bounds__(256) void k_gemm4(
    const void* __restrict__ A0, const void* __restrict__ A1,
    const void* __restrict__ B0, const void* __restrict__ B1,
    const float* __restrict__ bias, void* __restrict__ O0, void* __restrict__ O1)
{
    constexpr int CIN  = 1 << LOG2CIN;
    constexpr int HH   = HIN * HIN;
    constexpr int WM   = MT / 32;     // M-subtiles per wave (2 or 4)
    constexpr int AOPT = MT / 64;     // A k-octets staged per thread (1 or 2)
    constexpr int OSTEP = 256 / MT;   // octet stride between q's (4 or 2)

    __shared__ ushort Ah[2][4][MT][8], Al[2][4][MT][8];
    __shared__ ushort Bh[2][4][128][8], Bl[2][4][128][8];

    const int t    = threadIdx.x;
    const int lane = t & 63;
    const int wave = t >> 6;
    const int n0   = blockIdx.y * 128;
    const int sArow = t & (MT - 1), sAo0 = t / MT;
    const int sBrow = t & 127, sBo = t >> 7;
    const int rbA = sArow - lane;     // wave-uniform LDS row base for A
    const int rbB = sBrow - lane;     // wave-uniform LDS row base for B

    const ushort* Ahp = (const ushort*)A0;
    const ushort* Alp = (const ushort*)A1;
    size_t aoff = 0;                  // MODE 0: per-lane NHWC element offset
    const ushort* Ahg = nullptr;      // MODE 1: per-lane row pointers
    const ushort* Alg = nullptr;
    int b = 0, ptile = 0, kbeg = 0, kend = K;

    if (MODE == 0) {
        b = blockIdx.x / TPI;
        ptile = blockIdx.x - b * TPI;
        int pl = ptile * (MT / 4) + (sArow >> 2);
        int quad = sArow & 3;
        int py = 0, px = 0;
        if (pl < PPH * PPW) { py = pl / PPW; px = pl - py * PPW; }
        aoff = ((size_t)b * HH + (size_t)(2 * py + (quad >> 1)) * HIN
               + (2 * px + (quad & 1))) * CIN;
    } else {
        int arow = blockIdx.x * MT + sArow;
        Ahg = (const ushort*)A0 + (size_t)arow * K;
        Alg = (const ushort*)A1 + (size_t)arow * K;
        kbeg = blockIdx.z * KCH;
        kend = kbeg + KCH;
    }

    auto stage = [&](int kkx, int buf) {
        // ---- A: hi/lo planes, gload_lds direct ----
#pragma unroll
        for (int q = 0; q < AOPT; ++q) {
            const int ko = sAo0 + q * OSTEP;
            const int kb = kkx + ko * 8;
            if (MODE == 0) {
                const int r  = kb >> LOG2CIN;      // wave-uniform
                const int cb = kb & (CIN - 1);
                const int rh = (r * 11) >> 5;      // r/3 for r<9
                const int rw = r - 3 * rh;
                const size_t g = aoff + (size_t)(rh * HIN + rw) * CIN + cb;
                gl_lds16(Ahp + g, &Ah[buf][ko][rbA][0]);
                gl_lds16(Alp + g, &Al[buf][ko][rbA][0]);
            } else {
                gl_lds16(Ahg + kb, &Ah[buf][ko][rbA][0]);
                gl_lds16(Alg + kb, &Al[buf][ko][rbA][0]);
            }
        }
        // ---- B ----
        if (BPRE) {
#pragma unroll
            for (int q = 0; q < 2; ++q) {
                const int o = sBo + 2 * q;
                const int kb = kkx + o * 8;
                const size_t g = (size_t)(n0 + sBrow) * K + kb;
                gl_lds16((const ushort*)B0 + g, &Bh[buf][o][rbB][0]);
                gl_lds16((const ushort*)B1 + g, &Bl[buf][o][rbB][0]);
            }
        } else {
            // fallback: in-kernel split from f32 weights (ds_write path)
#pragma unroll
            for (int q = 0; q < 2; ++q) {
                const int o = sBo + 2 * q;
                const int kb = kkx + o * 8;
                V8 hb, lb;
                if (MODE == 0) {
                    const int r  = kb >> LOG2CIN;
                    const int cb = kb & (CIN - 1);
                    const float* bp = (const float*)B0
                        + (size_t)(n0 + sBrow) * K + (size_t)cb * 9 + r;
#pragma unroll
                    for (int j = 0; j < 8; ++j)
                        splitf(bp[9 * j], hb.s[j], lb.s[j]);
                } else {
                    const float* bp = (const float*)B0 + (size_t)kb * N + n0 + sBrow;
#pragma unroll
                    for (int j = 0; j < 8; ++j)
                        splitf(bp[(size_t)j * N], hb.s[j], lb.s[j]);
                }
                *(s8v*)&Bh[buf][o][sBrow][0] = hb.v;
                *(s8v*)&Bl[buf][o][sBrow][0] = lb.v;
            }
        }
    };

    f4v acc[WM][4];
    const f4v z4 = {0.f, 0.f, 0.f, 0.f};
#pragma unroll
    for (int i = 0; i < WM; ++i)
#pragma unroll
        for (int j = 0; j < 4; ++j) acc[i][j] = z4;

    // prologue: fill buf 0, wait (vmcnt(0) via syncthreads)
    stage(kbeg, 0);
    __syncthreads();

    int cur = 0;
    for (int kk = kbeg; kk < kend; kk += 32) {
        if (kk + 32 < kend)
            stage(kk + 32, cur ^ 1);   // async into other buffer; stays in
                                       // flight under this step's MFMAs
        const int fm = lane & 15;
        const int ko = lane >> 4;
        s8v a_h[WM], a_l[WM], b_h[4], b_l[4];
#pragma unroll
        for (int i = 0; i < WM; ++i) {
            a_h[i] = *(const s8v*)&Ah[cur][ko][(wave & 1) * (MT / 2) + i * 16 + fm][0];
            a_l[i] = *(const s8v*)&Al[cur][ko][(wave & 1) * (MT / 2) + i * 16 + fm][0];
        }
#pragma unroll
        for (int j = 0; j < 4; ++j) {
            b_h[j] = *(const s8v*)&Bh[cur][ko][(wave >> 1) * 64 + j * 16 + fm][0];
            b_l[j] = *(const s8v*)&Bl[cur][ko][(wave >> 1) * 64 + j * 16 + fm][0];
        }
#define MF(a_, b_, c_) c_ = __builtin_amdgcn_mfma_f32_16x16x32_bf16(a_, b_, c_, 0, 0, 0)
#pragma unroll
        for (int i = 0; i < WM; ++i)
#pragma unroll
            for (int j = 0; j < 4; ++j) {
                MF(a_h[i], b_h[j], acc[i][j]);
                MF(a_h[i], b_l[j], acc[i][j]);
                MF(a_l[i], b_h[j], acc[i][j]);
            }
#undef MF
        __syncthreads();   // vmcnt(0): prefetch landed; all reads of cur done
        cur ^= 1;
    }

    if (MODE == 0) {
        const int PP = PPH * PPW;
#pragma unroll
        for (int i = 0; i < WM; ++i)
#pragma unroll
            for (int j = 0; j < 4; ++j) {
                int p  = ptile * (MT / 4) + (wave & 1) * (MT / 8) + i * 4 + (lane >> 4);
                int oc = n0 + (wave >> 1) * 64 + j * 16 + (lane & 15);
                if (p < PP) {
                    f4v v = acc[i][j];
                    float m = fmaxf(fmaxf(v.x, v.y), fmaxf(v.z, v.w));
                    m = fmaxf(m + bias[oc], 0.f);
                    short h, l; splitf(m, h, l);
                    if (EPI == 0) {
                        // NHWC hi/lo planes
                        size_t o = ((size_t)b * PP + p) * COUT + oc;
                        ((ushort*)O0)[o] = (ushort)h;
                        ((ushort*)O1)[o] = (ushort)l;
                    } else {
                        // NCHW hi/lo planes (FC1 A layout)
                        size_t o = (size_t)(b * COUT + oc) * PP + p;
                        ((ushort*)O0)[o] = (ushort)h;
                        ((ushort*)O1)[o] = (ushort)l;
                    }
                }
            }
    } else {
        float* P = (float*)O0 + (size_t)blockIdx.z * 128 * N;
#pragma unroll
        for (int i = 0; i < WM; ++i)
#pragma unroll
            for (int j = 0; j < 4; ++j) {
                int n = n0 + (wave >> 1) * 64 + j * 16 + (lane & 15);
                int mb = blockIdx.x * MT + (wave & 1) * (MT / 2) + i * 16 + (lane >> 4) * 4;
                f4v v = acc[i][j];
                P[(size_t)(mb + 0) * N + n] = v.x;
                P[(size_t)(mb + 1) * N + n] = v.y;
                P[(size_t)(mb + 2) * N + n] = v.z;
                P[(size_t)(mb + 3) * N + n] = v.w;
            }
    }
}

// FC partial-sum epilogue: sum KS partials + bias + tanh; EFMT 1: split planes,
// EFMT 2: f32.
template<int EFMT>
__global__ void k_fc_epi2(const float* __restrict__ P, const float* __restrict__ bias,
                          ushort* __restrict__ oh, ushort* __restrict__ ol,
                          float* __restrict__ of, int MN, int N, int KS)
{
    int i = blockIdx.x * 256 + threadIdx.x;
    if (i >= MN) return;
    float s = 0.f;
    for (int z = 0; z < KS; ++z) s += P[(size_t)z * MN + i];
    s = tanhf(s + bias[i % N]);
    if (EFMT == 1) {
        short h, l; splitf(s, h, l);
        oh[i] = (ushort)h; ol[i] = (ushort)l;
    } else {
        of[i] = s;
    }
}

// FC3: (128x2048) x (2048x62) f32 vector, K-split partials.
__global__ __launch_bounds__(64) void k_fc3_part(
    const float* __restrict__ A, const float* __restrict__ B,
    float* __restrict__ P, int K, int N, int KS)
{
    const int m = blockIdx.x, kz = blockIdx.y;
    const int n = threadIdx.x;
    const int kchunk = K / KS;
    if (n < N) {
        float acc = 0.f;
        const float* Am = A + (size_t)m * K;
        const int ke = (kz + 1) * kchunk;
        for (int k = kz * kchunk; k < ke; ++k)
            acc = fmaf(Am[k], B[(size_t)k * N + n], acc);
        P[((size_t)kz * 128 + m) * N + n] = acc;
    }
}

__global__ void k_fc_epi(const float* __restrict__ P, const float* __restrict__ bias,
                         float* __restrict__ out, int MN, int N, int KS)
{
    int i = blockIdx.x * 256 + threadIdx.x;
    if (i >= MN) return;
    float s = 0.f;
    for (int z = 0; z < KS; ++z) s += P[(size_t)z * MN + i];
    out[i] = s + bias[i % N];
}

// Per-batch DMP segment prep. 1x128, thread = batch.
__global__ void k_traj_start(const float* __restrict__ p, const float* __restrict__ td,
                             float* __restrict__ starts, float* __restrict__ sa,
                             int* __restrict__ sidx)
{
    int b = threadIdx.x;
    const float* pb = p + b * 62;
    float cx = pb[0], cy = pb[1];
    for (int s = 0; s < 20; ++s) {
        float f  = pb[2 + 3 * s];
        float a0 = pb[3 + 3 * s];
        float a1 = pb[4 + 3 * s];
        int idx = (int)fminf(fmaxf(rintf(f), 0.f), 999.f);
        int bs = b * 20 + s;
        sidx[bs] = idx;
        sa[bs * 2 + 0] = a0;
        sa[bs * 2 + 1] = a1;
        starts[bs * 2 + 0] = cx;
        starts[bs * 2 + 1] = cy;
        cx += td[((size_t)idx * 200 + 199) * 2 + 0] * a0;
        cy += td[((size_t)idx * 200 + 199) * 2 + 1] * a1;
    }
}

__global__ void k_traj_main(const float* __restrict__ td, const float* __restrict__ starts,
                            const float* __restrict__ sa, const int* __restrict__ sidx,
                            float* __restrict__ out)
{
    int bs = blockIdx.x;
    int idx = sidx[bs];
    float a0 = sa[bs * 2 + 0], a1 = sa[bs * 2 + 1];
    float s0 = starts[bs * 2 + 0], s1 = starts[bs * 2 + 1];
    const float* row = td + (size_t)idx * 400;
    float* o = out + (size_t)bs * 400;
    for (int e = threadIdx.x; e < 400; e += blockDim.x) {
        float v = row[e];
        o[e] = (e & 1) ? fmaf(v, a1, s1) : fmaf(v, a0, s0);
    }
}

// ---------------------------------------------------------------------------
template<int BPRE>
static void run_all(void* const* d_in, float* out, char* ws, hipStream_t stream)
{
    const float* x   = (const float*)d_in[0];
    const float* w1  = (const float*)d_in[1];
    const float* b1  = (const float*)d_in[2];
    const float* w2  = (const float*)d_in[3];
    const float* b2  = (const float*)d_in[4];
    const float* w3  = (const float*)d_in[5];
    const float* b3  = (const float*)d_in[6];
    const float* w4  = (const float*)d_in[7];
    const float* b4  = (const float*)d_in[8];
    const float* fw1 = (const float*)d_in[9];
    const float* fb1 = (const float*)d_in[10];
    const float* fw2 = (const float*)d_in[11];
    const float* fb2 = (const float*)d_in[12];
    const float* fw3 = (const float*)d_in[13];
    const float* fb3 = (const float*)d_in[14];
    const float* td  = (const float*)d_in[15];

    // ---- workspace layout (bytes); activations = hi/lo bf16 NHWC planes ----
    ushort* h1h  = (ushort*)ws;                        // 39,337,984
    ushort* h1l  = (ushort*)(ws + 39337984ull);        // 39,337,984 (end 78,675,968)
    ushort* h2h  = (ushort*)(ws + 78675968ull);        // 17,334,272
    ushort* h2l  = (ushort*)(ws + 96010240ull);        // 17,334,272 (end 113,344,512)
    ushort* h3h  = (ushort*)ws;                        // 6,553,600 (h1 dead)
    ushort* h3l  = (ushort*)(ws + 6553600ull);         // 6,553,600 (end 13,107,200)
    ushort* fw1h = (ushort*)(ws + 13107200ull);        // 33,554,432
    ushort* fw1l = (ushort*)(ws + 46661632ull);        // 33,554,432
    ushort* h4h  = (ushort*)(ws + 80216064ull);        // 2,097,152 (NCHW planes)
    ushort* h4l  = (ushort*)(ws + 82313216ull);        // 2,097,152
    ushort* fw2h = (ushort*)(ws + 84410368ull);        // 8,388,608
    ushort* fw2l = (ushort*)(ws + 92798976ull);        // 8,388,608
    float*  part = (float*)(ws + 101187584ull);        // 8,388,608
    ushort* a1h  = (ushort*)(ws + 109576192ull);       // 524,288
    ushort* a1l  = (ushort*)(ws + 110100480ull);       // 524,288
    float*  a2   = (float*)(ws + 110624768ull);        // 1,048,576
    float*  p    = (float*)(ws + 111673344ull);
    float*  starts = (float*)(ws + 111705088ull);
    float*  sa   = (float*)(ws + 111725568ull);
    int*    sidx = (int*)(ws + 111746048ull);
    ushort* w2h = (ushort*)(ws + 113344512ull);
    ushort* w2l = (ushort*)(ws + 113491968ull);
    ushort* w3h = (ushort*)(ws + 113639424ull);
    ushort* w3l = (ushort*)(ws + 114229248ull);
    ushort* w4h = (ushort*)(ws + 114819072ull);
    ushort* w4l = (ushort*)(ws + 117178368ull);        // end 119,537,664

    if (BPRE) {   // permuted split: [n][ci*9+r] -> [n][r*CIN+ci]
        k_wsplit_perm<<<(73728 + 255) / 256, 256, 0, stream>>>(w2, w2h, w2l, 64, 73728);
        k_wsplit_perm<<<(294912 + 255) / 256, 256, 0, stream>>>(w3, w3h, w3l, 128, 294912);
        k_wsplit_perm<<<(1179648 + 255) / 256, 256, 0, stream>>>(w4, w4h, w4l, 256, 1179648);
    }

    // conv1: 3->64, 100 -> pool 49 (direct, NHWC hi/lo planes out)
    k_conv_pool_relu<3, 100, 49, 16, 256, 3, 64>
        <<<dim3(10, 4, 128), 256, 0, stream>>>(x, w1, b1, h1h, h1l);

    // conv2: 64->128, K=576, pooled 23x23=529 (17 tiles of 32 pooled), N=128
    k_gemm4<0, BPRE, 0, 6, 576, 576, 128, 49, 23, 23, 128, 17, 128>
        <<<dim3(17 * 128, 1), 256, 0, stream>>>(
            h1h, h1l, BPRE ? (const void*)w2h : (const void*)w2,
            BPRE ? (const void*)w2l : nullptr, b2, h2h, h2l);
    // conv3: 128->256, K=1152, pooled 10x10=100 (4 tiles of 32 pooled), N=256
    k_gemm4<0, BPRE, 0, 7, 1152, 1152, 256, 23, 10, 10, 256, 4, 128>
        <<<dim3(4 * 128, 2), 256, 0, stream>>>(
            h2h, h2l, BPRE ? (const void*)w3h : (const void*)w3,
            BPRE ? (const void*)w3l : nullptr, b3, h3h, h3l);

    if (BPRE) {   // h1/h2-head dead; build FC weight planes
        k_wsplitT<<<dim3(2048 / 32, 8192 / 32), 256, 0, stream>>>(fw1, fw1h, fw1l, 8192, 2048);
        k_wsplitT<<<dim3(2048 / 32, 2048 / 32), 256, 0, stream>>>(fw2, fw2h, fw2l, 2048, 2048);
    }

    // conv4: 256->512, K=2304, pooled 4x4 (1 tile/img), N=512 -> h4 NCHW planes
    k_gemm4<0, BPRE, 1, 8, 2304, 2304, 512, 10, 4, 4, 512, 1, 64>
        <<<dim3(128, 4), 256, 0, stream>>>(
            h3h, h3l, BPRE ? (const void*)w4h : (const void*)w4,
            BPRE ? (const void*)w4l : nullptr, b4, h4h, h4l);

    // FC1: (128x8192)x(8192x2048), KS=8 partials + tanh -> a1 planes
    k_gemm4<1, BPRE, 2, 0, 8192, 1024, 2048, 1, 1, 1, 1, 1, 64>
        <<<dim3(2, 16, 8), 256, 0, stream>>>(
            h4h, h4l, BPRE ? (const void*)fw1h : (const void*)fw1,
            BPRE ? (const void*)fw1l : nullptr, nullptr, part, nullptr);
    k_fc_epi2<1><<<(128 * 2048 + 255) / 256, 256, 0, stream>>>(
        part, fb1, a1h, a1l, nullptr, 128 * 2048, 2048, 8);
    // FC2: (128x2048)x(2048x2048), KS=8 partials + tanh -> a2 f32
    k_gemm4<1, BPRE, 2, 0, 2048, 256, 2048, 1, 1, 1, 1, 1, 64>
        <<<dim3(2, 16, 8), 256, 0, stream>>>(
            a1h, a1l, BPRE ? (const void*)fw2h : (const void*)fw2,
            BPRE ? (const void*)fw2l : nullptr, nullptr, part, nullptr);
    k_fc_epi2<2><<<(128 * 2048 + 255) / 256, 256, 0, stream>>>(
        part, fb2, nullptr, nullptr, a2, 128 * 2048, 2048, 8);

    // FC3 (f32 vector) + trajectory composition
    k_fc3_part<<<dim3(128, 4), 64, 0, stream>>>(a2, fw3, part, 2048, 62, 4);
    k_fc_epi<<<(128 * 62 + 255) / 256, 256, 0, stream>>>(
        part, fb3, p, 128 * 62, 62, 4);
    k_traj_start<<<1, 128, 0, stream>>>(p, td, starts, sa, sidx);
    k_traj_main<<<2560, 256, 0, stream>>>(td, starts, sa, sidx, out);
}

extern "C" void kernel_launch(void* const* d_in, const int* in_sizes, int n_in,
                              void* d_out, int out_size, void* d_ws, size_t ws_size,
                              hipStream_t stream)
{
    (void)in_sizes; (void)n_in; (void)out_size;
    if (ws_size >= 119537664ull)
        run_all<1>(d_in, (float*)d_out, (char*)d_ws, stream);
    else
        run_all<0>(d_in, (float*)d_out, (char*)d_ws, stream);
}

// Round 7
// 983.310 us; speedup vs baseline: 1.0281x; 1.0281x over previous
//
#include <hip/hip_runtime.h>
#include <hip/hip_bf16.h>

typedef __attribute__((ext_vector_type(8))) short s8v;
typedef __attribute__((ext_vector_type(4))) float f4v;
typedef unsigned short ushort;
typedef unsigned int uint;

union V8 { s8v v; short s[8]; };

__device__ __forceinline__ short f2bf(float v){
    union { __hip_bfloat16 b; short u; } x;
    x.b = __float2bfloat16(v);
    return x.u;
}
__device__ __forceinline__ float bf2f(short u){
    union { short u; __hip_bfloat16 b; } x;
    x.u = u;
    return __bfloat162float(x.b);
}
__device__ __forceinline__ void splitf(float v, short& h, short& l){
    h = f2bf(v);
    l = f2bf(v - bf2f(h));
}
__device__ __forceinline__ uint packsplit(float v){
    short h, l; splitf(v, h, l);
    return (uint)(ushort)h | ((uint)(ushort)l << 16);
}

// ---------------------------------------------------------------------------
// conv1 (CIN=3): direct conv + pool + ReLU -> NHWC interleaved-split u32.
// ---------------------------------------------------------------------------
template<int CIN, int HIN, int PH, int OCB, int SPT, int CICH, int COUT>
__global__ __launch_bounds__(SPT) void k_conv_pool_relu(
    const float* __restrict__ in, const float* __restrict__ w,
    const float* __restrict__ bias, uint* __restrict__ out)
{
    constexpr int WIN   = HIN;
    constexpr int PW    = PH;
    constexpr int WSTR  = CICH * 9 + 1;

    __shared__ float wsh[OCB * WSTR];

    const int b   = blockIdx.z;
    const int oc0 = blockIdx.y * OCB;
    const int t   = threadIdx.x;
    const int sp  = blockIdx.x * SPT + t;
    const bool active = sp < PH * PW;
    const int py = active ? (sp / PW) : 0;
    const int px = active ? (sp % PW) : 0;

    float acc[OCB][4];
#pragma unroll
    for (int j = 0; j < OCB; ++j)
        acc[j][0] = acc[j][1] = acc[j][2] = acc[j][3] = 0.f;

    const float* inb = in + (size_t)b * CIN * HIN * WIN;

    for (int c0 = 0; c0 < CIN; c0 += CICH) {
        __syncthreads();
        for (int i = t; i < OCB * CICH * 9; i += SPT) {
            int j = i / (CICH * 9);
            int r = i - j * (CICH * 9);
            wsh[j * WSTR + r] = w[((size_t)(oc0 + j) * CIN + c0) * 9 + r];
        }
        __syncthreads();

        for (int ci = 0; ci < CICH; ++ci) {
            const float* inc = inb + (size_t)(c0 + ci) * HIN * WIN
                             + (2 * py) * WIN + 2 * px;
            float patch[4][4];
#pragma unroll
            for (int r = 0; r < 4; ++r)
#pragma unroll
                for (int c = 0; c < 4; ++c)
                    patch[r][c] = inc[r * WIN + c];

#pragma unroll
            for (int j = 0; j < OCB; ++j) {
                const float* wp = &wsh[j * WSTR + ci * 9];
#pragma unroll
                for (int kh = 0; kh < 3; ++kh)
#pragma unroll
                    for (int kw = 0; kw < 3; ++kw) {
                        float wv = wp[kh * 3 + kw];
                        acc[j][0] = fmaf(patch[kh][kw],         wv, acc[j][0]);
                        acc[j][1] = fmaf(patch[kh][kw + 1],     wv, acc[j][1]);
                        acc[j][2] = fmaf(patch[kh + 1][kw],     wv, acc[j][2]);
                        acc[j][3] = fmaf(patch[kh + 1][kw + 1], wv, acc[j][3]);
                    }
            }
        }
    }

    if (active) {
        uint tmp[OCB];
#pragma unroll
        for (int j = 0; j < OCB; ++j) {
            float m = fmaxf(fmaxf(acc[j][0], acc[j][1]),
                            fmaxf(acc[j][2], acc[j][3]));
            m = fmaxf(m + bias[oc0 + j], 0.f);
            tmp[j] = packsplit(m);
        }
        // NHWC: [b][p][oc]
        uint* ob = out + ((size_t)b * PH * PW + sp) * COUT + oc0;
#pragma unroll
        for (int q = 0; q < OCB / 4; ++q)
            ((uint4*)ob)[q] = ((const uint4*)tmp)[q];
    }
}

// ---------------------------------------------------------------------------
// Conv weight split WITH K-permutation: w[n][ci*9+r] -> planes [n][r*CIN+ci].
// ---------------------------------------------------------------------------
__global__ void k_wsplit_perm(const float* __restrict__ w, ushort* __restrict__ oh,
                              ushort* __restrict__ ol, int CIN, int total)
{
    int i = blockIdx.x * 256 + threadIdx.x;
    if (i < total) {
        int K = CIN * 9;
        int n = i / K;
        int rem = i - n * K;
        int ci = rem / 9;
        int r = rem - 9 * ci;
        short h, l; splitf(w[i], h, l);
        size_t o = (size_t)n * K + r * CIN + ci;
        oh[o] = (ushort)h; ol[o] = (ushort)l;
    }
}

// Transpose+split: f32 [K][N] -> hi/lo ushort planes [n][k]. 32x32 tiles.
__global__ __launch_bounds__(256) void k_wsplitT(
    const float* __restrict__ B, ushort* __restrict__ oh, ushort* __restrict__ ol,
    int K, int N)
{
    __shared__ float tl[32][33];
    const int n0 = blockIdx.x * 32, k0 = blockIdx.y * 32;
    const int r = threadIdx.x >> 5, c = threadIdx.x & 31;
#pragma unroll
    for (int it = 0; it < 4; ++it) {
        int row = r + it * 8;
        tl[row][c] = B[(size_t)(k0 + row) * N + n0 + c];
    }
    __syncthreads();
#pragma unroll
    for (int it = 0; it < 4; ++it) {
        int a = r + it * 8;
        float v = tl[c][a];
        short h, l; splitf(v, h, l);
        size_t o = (size_t)(n0 + a) * K + k0 + c;
        oh[o] = (ushort)h; ol[o] = (ushort)l;
    }
}

// ---------------------------------------------------------------------------
// Split-bf16 MFMA GEMM v10: R2 structure (proven best) + IPB images/block.
// MT=128: tile 128x128, 4 waves, wave = 64x64 (4x4 subtiles), 48 MFMA/K-step.
// MT=64 : tile 64x128, wave = 32x64 (2x4 subtiles).
// IPB>1 (MODE 0): pack IPB images' pooled positions into one M-tile
//   (row block i covers image b+pl/PP, local position pl%PP).
// MODE 0: implicit-GEMM conv, NHWC interleaved-split u32 A; in-register
//   2x2 maxpool + bias + ReLU epilogue. EPI 0: NHWC u32; EPI 1: NCHW planes.
// MODE 1: FC partial (grid.z K-split), A/B hi-lo ushort planes, f32 partials.
// ---------------------------------------------------------------------------
template<int MODE, int BPRE, int EPI, int LOG2CIN, int K, int KCH, int N,
         int HIN, int PPH, int PPW, int COUT, int TPI, int MT, int IPB>
__global__ __launch_bounds__(256) void k_gemm4(
    const void* __restrict__ A0, const void* __restrict__ A1,
    const void* __restrict__ B0, const void* __restrict__ B1,
    const float* __restrict__ bias, void* __restrict__ O0, void* __restrict__ O1)
{
    constexpr int CIN  = 1 << LOG2CIN;
    constexpr int HH   = HIN * HIN;
    constexpr int PP   = PPH * PPW;
    constexpr int WM   = MT / 32;     // M-subtiles per wave (2 or 4)
    constexpr int AOPT = MT / 64;     // A-octets staged per thread (1 or 2)
    constexpr int OSTEP = 256 / MT;   // octet stride between q's (4 or 2)

    __shared__ short Ah[MT][40], Al[MT][40], Bh[128][40], Bl[128][40];

    const int t    = threadIdx.x;
    const int lane = t & 63;
    const int wave = t >> 6;
    const int n0   = blockIdx.y * 128;
    const int sArow = t & (MT - 1), sAo0 = t / MT;
    const int sBrow = t & 127, sBo = t >> 7;

    const uint*   ArI = nullptr;   // NHWC base at (img, y0, x0, 0)
    const ushort* Ahg = nullptr;
    const ushort* Alg = nullptr;
    int b = 0, ptile = 0, kbeg = 0, kend = K;

    if (MODE == 0) {
        int bb = blockIdx.x / TPI;
        ptile = blockIdx.x - bb * TPI;
        b = bb * IPB;                      // base image of this block
        int pl = ptile * (MT / 4) + (sArow >> 2);
        int quad = sArow & 3;
        int isub = 0, pll = pl;
        if (IPB > 1) {
            if (pl < IPB * PP) { isub = pl / PP; pll = pl - isub * PP; }
            else { isub = 0; pll = 0; }
        }
        int py = 0, px = 0;
        if (pll < PP) { py = pll / PPW; px = pll - py * PPW; }
        ArI = (const uint*)A0
            + ((size_t)(b + isub) * HH + (size_t)(2 * py + (quad >> 1)) * HIN
               + (2 * px + (quad & 1))) * CIN;
    } else {
        int arow = blockIdx.x * MT + sArow;
        Ahg = (const ushort*)A0 + (size_t)arow * K;
        Alg = (const ushort*)A1 + (size_t)arow * K;
        kbeg = blockIdx.z * KCH;
        kend = kbeg + KCH;
    }

    // ---- prefetch helpers ----
    auto pfA = [&](int kkx, V8* ha, V8* la) {
#pragma unroll
        for (int q = 0; q < AOPT; ++q) {
            const int kb = kkx + (sAo0 + q * OSTEP) * 8;
            if (MODE == 0) {
                const int r  = kb >> LOG2CIN;       // wave-uniform
                const int cb = kb & (CIN - 1);      // wave-uniform, multiple of 8
                const int rh = (r * 11) >> 5;       // r/3 for r<9
                const int rw = r - 3 * rh;
                const uint* g = ArI + (rh * HIN + rw) * CIN + cb;  // 32B contiguous
                uint4 v0 = *(const uint4*)g;
                uint4 v1 = *(const uint4*)(g + 4);
                uint vv[8] = {v0.x, v0.y, v0.z, v0.w, v1.x, v1.y, v1.z, v1.w};
#pragma unroll
                for (int j = 0; j < 8; ++j) {
                    ha[q].s[j] = (short)(vv[j] & 0xffffu);
                    la[q].s[j] = (short)(vv[j] >> 16);
                }
            } else {
                ha[q].v = *(const s8v*)(Ahg + kb);
                la[q].v = *(const s8v*)(Alg + kb);
            }
        }
    };
    auto pfB = [&](int kkx, V8* hb, V8* lb) {
#pragma unroll
        for (int q = 0; q < 2; ++q) {
            const int o = sBo + 2 * q;
            const int kb = kkx + o * 8;
            if (BPRE) {
                hb[q].v = *(const s8v*)((const ushort*)B0 + (size_t)(n0 + sBrow) * K + kb);
                lb[q].v = *(const s8v*)((const ushort*)B1 + (size_t)(n0 + sBrow) * K + kb);
            } else if (MODE == 0) {
                // fallback: permuted gather from f32 w[n][ci*9+r], stride 9
                const int r  = kb >> LOG2CIN;
                const int cb = kb & (CIN - 1);
                const float* bp = (const float*)B0
                    + (size_t)(n0 + sBrow) * K + (size_t)cb * 9 + r;
#pragma unroll
                for (int j = 0; j < 8; ++j)
                    splitf(bp[9 * j], hb[q].s[j], lb[q].s[j]);
            } else {
                const float* bp = (const float*)B0 + (size_t)kb * N + n0 + sBrow;
#pragma unroll
                for (int j = 0; j < 8; ++j)
                    splitf(bp[(size_t)j * N], hb[q].s[j], lb[q].s[j]);
            }
        }
    };

    f4v acc[WM][4];
    const f4v z4 = {0.f, 0.f, 0.f, 0.f};
#pragma unroll
    for (int i = 0; i < WM; ++i)
#pragma unroll
        for (int j = 0; j < 4; ++j) acc[i][j] = z4;

    V8 pAh[AOPT], pAl[AOPT], pBh[2], pBl[2];
    pfA(kbeg, pAh, pAl);
    pfB(kbeg, pBh, pBl);

    for (int kk = kbeg; kk < kend; kk += 32) {
        __syncthreads();                       // prev iter's frag reads done
#pragma unroll
        for (int q = 0; q < AOPT; ++q) {
            const int o = sAo0 + q * OSTEP;
            *(s8v*)&Ah[sArow][o * 8] = pAh[q].v;
            *(s8v*)&Al[sArow][o * 8] = pAl[q].v;
        }
#pragma unroll
        for (int q = 0; q < 2; ++q) {
            const int o = sBo + 2 * q;
            *(s8v*)&Bh[sBrow][o * 8] = pBh[q].v;
            *(s8v*)&Bl[sBrow][o * 8] = pBl[q].v;
        }
        if (kk + 32 < kend) {                  // overlap next loads with MFMA
            pfA(kk + 32, pAh, pAl);
            pfB(kk + 32, pBh, pBl);
        }
        __syncthreads();                       // LDS tile visible

        const int fm = lane & 15;
        const int fk = (lane >> 4) * 8;
        s8v a_h[WM], a_l[WM], b_h[4], b_l[4];
#pragma unroll
        for (int i = 0; i < WM; ++i) {
            a_h[i] = *(const s8v*)&Ah[(wave & 1) * (MT / 2) + i * 16 + fm][fk];
            a_l[i] = *(const s8v*)&Al[(wave & 1) * (MT / 2) + i * 16 + fm][fk];
        }
#pragma unroll
        for (int j = 0; j < 4; ++j) {
            b_h[j] = *(const s8v*)&Bh[(wave >> 1) * 64 + j * 16 + fm][fk];
            b_l[j] = *(const s8v*)&Bl[(wave >> 1) * 64 + j * 16 + fm][fk];
        }
#define MF(a_, b_, c_) c_ = __builtin_amdgcn_mfma_f32_16x16x32_bf16(a_, b_, c_, 0, 0, 0)
#pragma unroll
        for (int i = 0; i < WM; ++i)
#pragma unroll
            for (int j = 0; j < 4; ++j) {
                MF(a_h[i], b_h[j], acc[i][j]);
                MF(a_h[i], b_l[j], acc[i][j]);
                MF(a_l[i], b_h[j], acc[i][j]);
            }
#undef MF
    }

    if (MODE == 0) {
#pragma unroll
        for (int i = 0; i < WM; ++i)
#pragma unroll
            for (int j = 0; j < 4; ++j) {
                int p  = ptile * (MT / 4) + (wave & 1) * (MT / 8) + i * 4 + (lane >> 4);
                int oc = n0 + (wave >> 1) * 64 + j * 16 + (lane & 15);
                if (p < IPB * PP) {
                    int isub = (IPB > 1) ? (p / PP) : 0;
                    int pp   = p - isub * PP;
                    int img  = b + isub;
                    f4v v = acc[i][j];
                    float m = fmaxf(fmaxf(v.x, v.y), fmaxf(v.z, v.w));
                    m = fmaxf(m + bias[oc], 0.f);
                    if (EPI == 0) {
                        // NHWC interleaved u32 (consecutive oc per lane-group)
                        ((uint*)O0)[((size_t)img * PP + pp) * COUT + oc] = packsplit(m);
                    } else {
                        // NCHW hi/lo planes (FC1 A layout)
                        size_t o = (size_t)(img * COUT + oc) * PP + pp;
                        short h, l; splitf(m, h, l);
                        ((ushort*)O0)[o] = (ushort)h;
                        ((ushort*)O1)[o] = (ushort)l;
                    }
                }
            }
    } else {
        float* P = (float*)O0 + (size_t)blockIdx.z * 128 * N;
#pragma unroll
        for (int i = 0; i < WM; ++i)
#pragma unroll
            for (int j = 0; j < 4; ++j) {
                int n = n0 + (wave >> 1) * 64 + j * 16 + (lane & 15);
                int mb = blockIdx.x * MT + (wave & 1) * (MT / 2) + i * 16 + (lane >> 4) * 4;
                f4v v = acc[i][j];
                P[(size_t)(mb + 0) * N + n] = v.x;
                P[(size_t)(mb + 1) * N + n] = v.y;
                P[(size_t)(mb + 2) * N + n] = v.z;
                P[(size_t)(mb + 3) * N + n] = v.w;
            }
    }
}

// FC partial-sum epilogue: sum KS partials + bias + tanh; EFMT 1: split planes,
// EFMT 2: f32.
template<int EFMT>
__global__ void k_fc_epi2(const float* __restrict__ P, const float* __restrict__ bias,
                          ushort* __restrict__ oh, ushort* __restrict__ ol,
                          float* __restrict__ of, int MN, int N, int KS)
{
    int i = blockIdx.x * 256 + threadIdx.x;
    if (i >= MN) return;
    float s = 0.f;
    for (int z = 0; z < KS; ++z) s += P[(size_t)z * MN + i];
    s = tanhf(s + bias[i % N]);
    if (EFMT == 1) {
        short h, l; splitf(s, h, l);
        oh[i] = (ushort)h; ol[i] = (ushort)l;
    } else {
        of[i] = s;
    }
}

// FC3: (128x2048) x (2048x62) f32 vector, K-split partials.
__global__ __launch_bounds__(64) void k_fc3_part(
    const float* __restrict__ A, const float* __restrict__ B,
    float* __restrict__ P, int K, int N, int KS)
{
    const int m = blockIdx.x, kz = blockIdx.y;
    const int n = threadIdx.x;
    const int kchunk = K / KS;
    if (n < N) {
        float acc = 0.f;
        const float* Am = A + (size_t)m * K;
        const int ke = (kz + 1) * kchunk;
        for (int k = kz * kchunk; k < ke; ++k)
            acc = fmaf(Am[k], B[(size_t)k * N + n], acc);
        P[((size_t)kz * 128 + m) * N + n] = acc;
    }
}

__global__ void k_fc_epi(const float* __restrict__ P, const float* __restrict__ bias,
                         float* __restrict__ out, int MN, int N, int KS)
{
    int i = blockIdx.x * 256 + threadIdx.x;
    if (i >= MN) return;
    float s = 0.f;
    for (int z = 0; z < KS; ++z) s += P[(size_t)z * MN + i];
    out[i] = s + bias[i % N];
}

// Per-batch DMP segment prep. 1x128, thread = batch.
__global__ void k_traj_start(const float* __restrict__ p, const float* __restrict__ td,
                             float* __restrict__ starts, float* __restrict__ sa,
                             int* __restrict__ sidx)
{
    int b = threadIdx.x;
    const float* pb = p + b * 62;
    float cx = pb[0], cy = pb[1];
    for (int s = 0; s < 20; ++s) {
        float f  = pb[2 + 3 * s];
        float a0 = pb[3 + 3 * s];
        float a1 = pb[4 + 3 * s];
        int idx = (int)fminf(fmaxf(rintf(f), 0.f), 999.f);
        int bs = b * 20 + s;
        sidx[bs] = idx;
        sa[bs * 2 + 0] = a0;
        sa[bs * 2 + 1] = a1;
        starts[bs * 2 + 0] = cx;
        starts[bs * 2 + 1] = cy;
        cx += td[((size_t)idx * 200 + 199) * 2 + 0] * a0;
        cy += td[((size_t)idx * 200 + 199) * 2 + 1] * a1;
    }
}

__global__ void k_traj_main(const float* __restrict__ td, const float* __restrict__ starts,
                            const float* __restrict__ sa, const int* __restrict__ sidx,
                            float* __restrict__ out)
{
    int bs = blockIdx.x;
    int idx = sidx[bs];
    float a0 = sa[bs * 2 + 0], a1 = sa[bs * 2 + 1];
    float s0 = starts[bs * 2 + 0], s1 = starts[bs * 2 + 1];
    const float* row = td + (size_t)idx * 400;
    float* o = out + (size_t)bs * 400;
    for (int e = threadIdx.x; e < 400; e += blockDim.x) {
        float v = row[e];
        o[e] = (e & 1) ? fmaf(v, a1, s1) : fmaf(v, a0, s0);
    }
}

// ---------------------------------------------------------------------------
template<int BPRE>
static void run_all(void* const* d_in, float* out, char* ws, hipStream_t stream)
{
    const float* x   = (const float*)d_in[0];
    const float* w1  = (const float*)d_in[1];
    const float* b1  = (const float*)d_in[2];
    const float* w2  = (const float*)d_in[3];
    const float* b2  = (const float*)d_in[4];
    const float* w3  = (const float*)d_in[5];
    const float* b3  = (const float*)d_in[6];
    const float* w4  = (const float*)d_in[7];
    const float* b4  = (const float*)d_in[8];
    const float* fw1 = (const float*)d_in[9];
    const float* fb1 = (const float*)d_in[10];
    const float* fw2 = (const float*)d_in[11];
    const float* fb2 = (const float*)d_in[12];
    const float* fw3 = (const float*)d_in[13];
    const float* fb3 = (const float*)d_in[14];
    const float* td  = (const float*)d_in[15];

    // ---- workspace layout (bytes), all activation tensors NHWC ----
    uint*   h1   = (uint*)ws;                          // [0, 78,675,968)
    uint*   h2   = (uint*)(ws + 78675968ull);          // 34,668,544
    uint*   h3   = (uint*)ws;                          // [0, 13,107,200)
    ushort* fw1h = (ushort*)(ws + 13107200ull);        // 33,554,432
    ushort* fw1l = (ushort*)(ws + 46661632ull);        // 33,554,432
    ushort* h4h  = (ushort*)(ws + 80216064ull);        // 2,097,152 (NCHW planes)
    ushort* h4l  = (ushort*)(ws + 82313216ull);        // 2,097,152
    ushort* fw2h = (ushort*)(ws + 84410368ull);        // 8,388,608
    ushort* fw2l = (ushort*)(ws + 92798976ull);        // 8,388,608
    float*  part = (float*)(ws + 101187584ull);        // 8,388,608
    ushort* a1h  = (ushort*)(ws + 109576192ull);       // 524,288
    ushort* a1l  = (ushort*)(ws + 110100480ull);       // 524,288
    float*  a2   = (float*)(ws + 110624768ull);        // 1,048,576
    float*  p    = (float*)(ws + 111673344ull);
    float*  starts = (float*)(ws + 111705088ull);
    float*  sa   = (float*)(ws + 111725568ull);
    int*    sidx = (int*)(ws + 111746048ull);
    ushort* w2h = (ushort*)(ws + 113344512ull);
    ushort* w2l = (ushort*)(ws + 113491968ull);
    ushort* w3h = (ushort*)(ws + 113639424ull);
    ushort* w3l = (ushort*)(ws + 114229248ull);
    ushort* w4h = (ushort*)(ws + 114819072ull);
    ushort* w4l = (ushort*)(ws + 117178368ull);        // end 119,537,664

    if (BPRE) {   // permuted split: [n][ci*9+r] -> [n][r*CIN+ci]
        k_wsplit_perm<<<(73728 + 255) / 256, 256, 0, stream>>>(w2, w2h, w2l, 64, 73728);
        k_wsplit_perm<<<(294912 + 255) / 256, 256, 0, stream>>>(w3, w3h, w3l, 128, 294912);
        k_wsplit_perm<<<(1179648 + 255) / 256, 256, 0, stream>>>(w4, w4h, w4l, 256, 1179648);
    }

    // conv1: 3->64, 100 -> pool 49 (direct, NHWC out)
    k_conv_pool_relu<3, 100, 49, 16, 256, 3, 64>
        <<<dim3(10, 4, 128), 256, 0, stream>>>(x, w1, b1, h1);

    // conv2: 64->128, K=576, pooled 23x23=529 (17 tiles of 32 pooled), N=128
    k_gemm4<0, BPRE, 0, 6, 576, 576, 128, 49, 23, 23, 128, 17, 128, 1>
        <<<dim3(17 * 128, 1), 256, 0, stream>>>(
            h1, nullptr, BPRE ? (const void*)w2h : (const void*)w2,
            BPRE ? (const void*)w2l : nullptr, b2, h2, nullptr);
    // conv3: 128->256, K=1152, pooled 10x10=100 (4 tiles of 32 pooled), N=256
    k_gemm4<0, BPRE, 0, 7, 1152, 1152, 256, 23, 10, 10, 256, 4, 128, 1>
        <<<dim3(4 * 128, 2), 256, 0, stream>>>(
            h2, nullptr, BPRE ? (const void*)w3h : (const void*)w3,
            BPRE ? (const void*)w3l : nullptr, b3, h3, nullptr);

    if (BPRE) {   // h1/h2-head dead; build FC weight planes
        k_wsplitT<<<dim3(2048 / 32, 8192 / 32), 256, 0, stream>>>(fw1, fw1h, fw1l, 8192, 2048);
        k_wsplitT<<<dim3(2048 / 32, 2048 / 32), 256, 0, stream>>>(fw2, fw2h, fw2l, 2048, 2048);
    }

    // conv4: 256->512, K=2304, pooled 4x4 (IPB=2 images per 128-row tile),
    // N=512 -> h4 NCHW planes
    k_gemm4<0, BPRE, 1, 8, 2304, 2304, 512, 10, 4, 4, 512, 1, 128, 2>
        <<<dim3(64, 4), 256, 0, stream>>>(
            h3, nullptr, BPRE ? (const void*)w4h : (const void*)w4,
            BPRE ? (const void*)w4l : nullptr, b4, h4h, h4l);

    // FC1: (128x8192)x(8192x2048), MT=128 single M-tile, KS=8 partials + tanh
    k_gemm4<1, BPRE, 2, 0, 8192, 1024, 2048, 1, 1, 1, 1, 1, 128, 1>
        <<<dim3(1, 16, 8), 256, 0, stream>>>(
            h4h, h4l, BPRE ? (const void*)fw1h : (const void*)fw1,
            BPRE ? (const void*)fw1l : nullptr, nullptr, part, nullptr);
    k_fc_epi2<1><<<(128 * 2048 + 255) / 256, 256, 0, stream>>>(
        part, fb1, a1h, a1l, nullptr, 128 * 2048, 2048, 8);
    // FC2: (128x2048)x(2048x2048), MT=128, KS=8 partials + tanh -> a2 f32
    k_gemm4<1, BPRE, 2, 0, 2048, 256, 2048, 1, 1, 1, 1, 1, 128, 1>
        <<<dim3(1, 16, 8), 256, 0, stream>>>(
            a1h, a1l, BPRE ? (const void*)fw2h : (const void*)fw2,
            BPRE ? (const void*)fw2l : nullptr, nullptr, part, nullptr);
    k_fc_epi2<2><<<(128 * 2048 + 255) / 256, 256, 0, stream>>>(
        part, fb2, nullptr, nullptr, a2, 128 * 2048, 2048, 8);

    // FC3 (f32 vector) + trajectory composition
    k_fc3_part<<<dim3(128, 4), 64, 0, stream>>>(a2, fw3, part, 2048, 62, 4);
    k_fc_epi<<<(128 * 62 + 255) / 256, 256, 0, stream>>>(
        part, fb3, p, 128 * 62, 62, 4);
    k_traj_start<<<1, 128, 0, stream>>>(p, td, starts, sa, sidx);
    k_traj_main<<<2560, 256, 0, stream>>>(td, starts, sa, sidx, out);
}

extern "C" void kernel_launch(void* const* d_in, const int* in_sizes, int n_in,
                              void* d_out, int out_size, void* d_ws, size_t ws_size,
                              hipStream_t stream)
{
    (void)in_sizes; (void)n_in; (void)out_size;
    if (ws_size >= 119537664ull)
        run_all<1>(d_in, (float*)d_out, (char*)d_ws, stream);
    else
        run_all<0>(d_in, (float*)d_out, (char*)d_ws, stream);
}

// Round 8
// 967.053 us; speedup vs baseline: 1.0454x; 1.0168x over previous
//
#include <hip/hip_runtime.h>
#include <hip/hip_bf16.h>

typedef __attribute__((ext_vector_type(8))) short s8v;
typedef __attribute__((ext_vector_type(4))) float f4v;
typedef unsigned short ushort;
typedef unsigned int uint;

union V8 { s8v v; short s[8]; };

__device__ __forceinline__ short f2bf(float v){
    union { __hip_bfloat16 b; short u; } x;
    x.b = __float2bfloat16(v);
    return x.u;
}
__device__ __forceinline__ float bf2f(short u){
    union { short u; __hip_bfloat16 b; } x;
    x.u = u;
    return __bfloat162float(x.b);
}
__device__ __forceinline__ void splitf(float v, short& h, short& l){
    h = f2bf(v);
    l = f2bf(v - bf2f(h));
}
__device__ __forceinline__ uint packsplit(float v){
    short h, l; splitf(v, h, l);
    return (uint)(ushort)h | ((uint)(ushort)l << 16);
}

// ---------------------------------------------------------------------------
// conv1 (CIN=3): direct conv + pool + ReLU -> NHWC interleaved-split u32.
// ---------------------------------------------------------------------------
template<int CIN, int HIN, int PH, int OCB, int SPT, int CICH, int COUT>
__global__ __launch_bounds__(SPT) void k_conv_pool_relu(
    const float* __restrict__ in, const float* __restrict__ w,
    const float* __restrict__ bias, uint* __restrict__ out)
{
    constexpr int WIN   = HIN;
    constexpr int PW    = PH;
    constexpr int WSTR  = CICH * 9 + 1;

    __shared__ float wsh[OCB * WSTR];

    const int b   = blockIdx.z;
    const int oc0 = blockIdx.y * OCB;
    const int t   = threadIdx.x;
    const int sp  = blockIdx.x * SPT + t;
    const bool active = sp < PH * PW;
    const int py = active ? (sp / PW) : 0;
    const int px = active ? (sp % PW) : 0;

    float acc[OCB][4];
#pragma unroll
    for (int j = 0; j < OCB; ++j)
        acc[j][0] = acc[j][1] = acc[j][2] = acc[j][3] = 0.f;

    const float* inb = in + (size_t)b * CIN * HIN * WIN;

    for (int c0 = 0; c0 < CIN; c0 += CICH) {
        __syncthreads();
        for (int i = t; i < OCB * CICH * 9; i += SPT) {
            int j = i / (CICH * 9);
            int r = i - j * (CICH * 9);
            wsh[j * WSTR + r] = w[((size_t)(oc0 + j) * CIN + c0) * 9 + r];
        }
        __syncthreads();

        for (int ci = 0; ci < CICH; ++ci) {
            const float* inc = inb + (size_t)(c0 + ci) * HIN * WIN
                             + (2 * py) * WIN + 2 * px;
            float patch[4][4];
#pragma unroll
            for (int r = 0; r < 4; ++r)
#pragma unroll
                for (int c = 0; c < 4; ++c)
                    patch[r][c] = inc[r * WIN + c];

#pragma unroll
            for (int j = 0; j < OCB; ++j) {
                const float* wp = &wsh[j * WSTR + ci * 9];
#pragma unroll
                for (int kh = 0; kh < 3; ++kh)
#pragma unroll
                    for (int kw = 0; kw < 3; ++kw) {
                        float wv = wp[kh * 3 + kw];
                        acc[j][0] = fmaf(patch[kh][kw],         wv, acc[j][0]);
                        acc[j][1] = fmaf(patch[kh][kw + 1],     wv, acc[j][1]);
                        acc[j][2] = fmaf(patch[kh + 1][kw],     wv, acc[j][2]);
                        acc[j][3] = fmaf(patch[kh + 1][kw + 1], wv, acc[j][3]);
                    }
            }
        }
    }

    if (active) {
        uint tmp[OCB];
#pragma unroll
        for (int j = 0; j < OCB; ++j) {
            float m = fmaxf(fmaxf(acc[j][0], acc[j][1]),
                            fmaxf(acc[j][2], acc[j][3]));
            m = fmaxf(m + bias[oc0 + j], 0.f);
            tmp[j] = packsplit(m);
        }
        // NHWC: [b][p][oc]
        uint* ob = out + ((size_t)b * PH * PW + sp) * COUT + oc0;
#pragma unroll
        for (int q = 0; q < OCB / 4; ++q)
            ((uint4*)ob)[q] = ((const uint4*)tmp)[q];
    }
}

// ---------------------------------------------------------------------------
// Conv weight split WITH K-permutation: w[n][ci*9+r] -> planes [n][r*CIN+ci].
// ---------------------------------------------------------------------------
__global__ void k_wsplit_perm(const float* __restrict__ w, ushort* __restrict__ oh,
                              ushort* __restrict__ ol, int CIN, int total)
{
    int i = blockIdx.x * 256 + threadIdx.x;
    if (i < total) {
        int K = CIN * 9;
        int n = i / K;
        int rem = i - n * K;
        int ci = rem / 9;
        int r = rem - 9 * ci;
        short h, l; splitf(w[i], h, l);
        size_t o = (size_t)n * K + r * CIN + ci;
        oh[o] = (ushort)h; ol[o] = (ushort)l;
    }
}

// Transpose+split: f32 [K][N] -> hi/lo ushort planes [n][k]. 32x32 tiles.
__global__ __launch_bounds__(256) void k_wsplitT(
    const float* __restrict__ B, ushort* __restrict__ oh, ushort* __restrict__ ol,
    int K, int N)
{
    __shared__ float tl[32][33];
    const int n0 = blockIdx.x * 32, k0 = blockIdx.y * 32;
    const int r = threadIdx.x >> 5, c = threadIdx.x & 31;
#pragma unroll
    for (int it = 0; it < 4; ++it) {
        int row = r + it * 8;
        tl[row][c] = B[(size_t)(k0 + row) * N + n0 + c];
    }
    __syncthreads();
#pragma unroll
    for (int it = 0; it < 4; ++it) {
        int a = r + it * 8;
        float v = tl[c][a];
        short h, l; splitf(v, h, l);
        size_t o = (size_t)(n0 + a) * K + k0 + c;
        oh[o] = (ushort)h; ol[o] = (ushort)l;
    }
}

// ---------------------------------------------------------------------------
// Split-bf16 MFMA GEMM v10: R2 structure (proven best) + IPB images/block.
// MT=128: tile 128x128, 4 waves, wave = 64x64 (4x4 subtiles), 48 MFMA/K-step.
// MT=64 : tile 64x128, wave = 32x64 (2x4 subtiles).
// IPB>1 (MODE 0): pack IPB images' pooled positions into one M-tile.
// MODE 0: implicit-GEMM conv, NHWC interleaved-split u32 A; in-register
//   2x2 maxpool + bias + ReLU epilogue. EPI 0: NHWC u32; EPI 1: NCHW planes.
// MODE 1: FC partial (grid.z K-split), A/B hi-lo ushort planes, f32 partials.
// ---------------------------------------------------------------------------
template<int MODE, int BPRE, int EPI, int LOG2CIN, int K, int KCH, int N,
         int HIN, int PPH, int PPW, int COUT, int TPI, int MT, int IPB>
__global__ __launch_bounds__(256) void k_gemm4(
    const void* __restrict__ A0, const void* __restrict__ A1,
    const void* __restrict__ B0, const void* __restrict__ B1,
    const float* __restrict__ bias, void* __restrict__ O0, void* __restrict__ O1)
{
    constexpr int CIN  = 1 << LOG2CIN;
    constexpr int HH   = HIN * HIN;
    constexpr int PP   = PPH * PPW;
    constexpr int WM   = MT / 32;     // M-subtiles per wave (2 or 4)
    constexpr int AOPT = MT / 64;     // A-octets staged per thread (1 or 2)
    constexpr int OSTEP = 256 / MT;   // octet stride between q's (4 or 2)

    __shared__ short Ah[MT][40], Al[MT][40], Bh[128][40], Bl[128][40];

    const int t    = threadIdx.x;
    const int lane = t & 63;
    const int wave = t >> 6;
    const int n0   = blockIdx.y * 128;
    const int sArow = t & (MT - 1), sAo0 = t / MT;
    const int sBrow = t & 127, sBo = t >> 7;

    const uint*   ArI = nullptr;   // NHWC base at (img, y0, x0, 0)
    const ushort* Ahg = nullptr;
    const ushort* Alg = nullptr;
    int b = 0, ptile = 0, kbeg = 0, kend = K;

    if (MODE == 0) {
        int bb = blockIdx.x / TPI;
        ptile = blockIdx.x - bb * TPI;
        b = bb * IPB;                      // base image of this block
        int pl = ptile * (MT / 4) + (sArow >> 2);
        int quad = sArow & 3;
        int isub = 0, pll = pl;
        if (IPB > 1) {
            if (pl < IPB * PP) { isub = pl / PP; pll = pl - isub * PP; }
            else { isub = 0; pll = 0; }
        }
        int py = 0, px = 0;
        if (pll < PP) { py = pll / PPW; px = pll - py * PPW; }
        ArI = (const uint*)A0
            + ((size_t)(b + isub) * HH + (size_t)(2 * py + (quad >> 1)) * HIN
               + (2 * px + (quad & 1))) * CIN;
    } else {
        int arow = blockIdx.x * MT + sArow;
        Ahg = (const ushort*)A0 + (size_t)arow * K;
        Alg = (const ushort*)A1 + (size_t)arow * K;
        kbeg = blockIdx.z * KCH;
        kend = kbeg + KCH;
    }

    // ---- prefetch helpers ----
    auto pfA = [&](int kkx, V8* ha, V8* la) {
#pragma unroll
        for (int q = 0; q < AOPT; ++q) {
            const int kb = kkx + (sAo0 + q * OSTEP) * 8;
            if (MODE == 0) {
                const int r  = kb >> LOG2CIN;       // wave-uniform
                const int cb = kb & (CIN - 1);      // wave-uniform, multiple of 8
                const int rh = (r * 11) >> 5;       // r/3 for r<9
                const int rw = r - 3 * rh;
                const uint* g = ArI + (rh * HIN + rw) * CIN + cb;  // 32B contiguous
                uint4 v0 = *(const uint4*)g;
                uint4 v1 = *(const uint4*)(g + 4);
                uint vv[8] = {v0.x, v0.y, v0.z, v0.w, v1.x, v1.y, v1.z, v1.w};
#pragma unroll
                for (int j = 0; j < 8; ++j) {
                    ha[q].s[j] = (short)(vv[j] & 0xffffu);
                    la[q].s[j] = (short)(vv[j] >> 16);
                }
            } else {
                ha[q].v = *(const s8v*)(Ahg + kb);
                la[q].v = *(const s8v*)(Alg + kb);
            }
        }
    };
    auto pfB = [&](int kkx, V8* hb, V8* lb) {
#pragma unroll
        for (int q = 0; q < 2; ++q) {
            const int o = sBo + 2 * q;
            const int kb = kkx + o * 8;
            if (BPRE) {
                hb[q].v = *(const s8v*)((const ushort*)B0 + (size_t)(n0 + sBrow) * K + kb);
                lb[q].v = *(const s8v*)((const ushort*)B1 + (size_t)(n0 + sBrow) * K + kb);
            } else if (MODE == 0) {
                // fallback: permuted gather from f32 w[n][ci*9+r], stride 9
                const int r  = kb >> LOG2CIN;
                const int cb = kb & (CIN - 1);
                const float* bp = (const float*)B0
                    + (size_t)(n0 + sBrow) * K + (size_t)cb * 9 + r;
#pragma unroll
                for (int j = 0; j < 8; ++j)
                    splitf(bp[9 * j], hb[q].s[j], lb[q].s[j]);
            } else {
                const float* bp = (const float*)B0 + (size_t)kb * N + n0 + sBrow;
#pragma unroll
                for (int j = 0; j < 8; ++j)
                    splitf(bp[(size_t)j * N], hb[q].s[j], lb[q].s[j]);
            }
        }
    };

    f4v acc[WM][4];
    const f4v z4 = {0.f, 0.f, 0.f, 0.f};
#pragma unroll
    for (int i = 0; i < WM; ++i)
#pragma unroll
        for (int j = 0; j < 4; ++j) acc[i][j] = z4;

    V8 pAh[AOPT], pAl[AOPT], pBh[2], pBl[2];
    pfA(kbeg, pAh, pAl);
    pfB(kbeg, pBh, pBl);

    for (int kk = kbeg; kk < kend; kk += 32) {
        __syncthreads();                       // prev iter's frag reads done
#pragma unroll
        for (int q = 0; q < AOPT; ++q) {
            const int o = sAo0 + q * OSTEP;
            *(s8v*)&Ah[sArow][o * 8] = pAh[q].v;
            *(s8v*)&Al[sArow][o * 8] = pAl[q].v;
        }
#pragma unroll
        for (int q = 0; q < 2; ++q) {
            const int o = sBo + 2 * q;
            *(s8v*)&Bh[sBrow][o * 8] = pBh[q].v;
            *(s8v*)&Bl[sBrow][o * 8] = pBl[q].v;
        }
        if (kk + 32 < kend) {                  // overlap next loads with MFMA
            pfA(kk + 32, pAh, pAl);
            pfB(kk + 32, pBh, pBl);
        }
        __syncthreads();                       // LDS tile visible

        const int fm = lane & 15;
        const int fk = (lane >> 4) * 8;
        s8v a_h[WM], a_l[WM], b_h[4], b_l[4];
#pragma unroll
        for (int i = 0; i < WM; ++i) {
            a_h[i] = *(const s8v*)&Ah[(wave & 1) * (MT / 2) + i * 16 + fm][fk];
            a_l[i] = *(const s8v*)&Al[(wave & 1) * (MT / 2) + i * 16 + fm][fk];
        }
#pragma unroll
        for (int j = 0; j < 4; ++j) {
            b_h[j] = *(const s8v*)&Bh[(wave >> 1) * 64 + j * 16 + fm][fk];
            b_l[j] = *(const s8v*)&Bl[(wave >> 1) * 64 + j * 16 + fm][fk];
        }
#define MF(a_, b_, c_) c_ = __builtin_amdgcn_mfma_f32_16x16x32_bf16(a_, b_, c_, 0, 0, 0)
#pragma unroll
        for (int i = 0; i < WM; ++i)
#pragma unroll
            for (int j = 0; j < 4; ++j) {
                MF(a_h[i], b_h[j], acc[i][j]);
                MF(a_h[i], b_l[j], acc[i][j]);
                MF(a_l[i], b_h[j], acc[i][j]);
            }
#undef MF
    }

    if (MODE == 0) {
#pragma unroll
        for (int i = 0; i < WM; ++i)
#pragma unroll
            for (int j = 0; j < 4; ++j) {
                int p  = ptile * (MT / 4) + (wave & 1) * (MT / 8) + i * 4 + (lane >> 4);
                int oc = n0 + (wave >> 1) * 64 + j * 16 + (lane & 15);
                if (p < IPB * PP) {
                    int isub = (IPB > 1) ? (p / PP) : 0;
                    int pp   = p - isub * PP;
                    int img  = b + isub;
                    f4v v = acc[i][j];
                    float m = fmaxf(fmaxf(v.x, v.y), fmaxf(v.z, v.w));
                    m = fmaxf(m + bias[oc], 0.f);
                    if (EPI == 0) {
                        // NHWC interleaved u32 (consecutive oc per lane-group)
                        ((uint*)O0)[((size_t)img * PP + pp) * COUT + oc] = packsplit(m);
                    } else {
                        // NCHW hi/lo planes (FC1 A layout)
                        size_t o = (size_t)(img * COUT + oc) * PP + pp;
                        short h, l; splitf(m, h, l);
                        ((ushort*)O0)[o] = (ushort)h;
                        ((ushort*)O1)[o] = (ushort)l;
                    }
                }
            }
    } else {
        float* P = (float*)O0 + (size_t)blockIdx.z * 128 * N;
#pragma unroll
        for (int i = 0; i < WM; ++i)
#pragma unroll
            for (int j = 0; j < 4; ++j) {
                int n = n0 + (wave >> 1) * 64 + j * 16 + (lane & 15);
                int mb = blockIdx.x * MT + (wave & 1) * (MT / 2) + i * 16 + (lane >> 4) * 4;
                f4v v = acc[i][j];
                P[(size_t)(mb + 0) * N + n] = v.x;
                P[(size_t)(mb + 1) * N + n] = v.y;
                P[(size_t)(mb + 2) * N + n] = v.z;
                P[(size_t)(mb + 3) * N + n] = v.w;
            }
    }
}

// FC partial-sum epilogue: sum KS partials + bias + tanh; EFMT 1: split planes,
// EFMT 2: f32.
template<int EFMT>
__global__ void k_fc_epi2(const float* __restrict__ P, const float* __restrict__ bias,
                          ushort* __restrict__ oh, ushort* __restrict__ ol,
                          float* __restrict__ of, int MN, int N, int KS)
{
    int i = blockIdx.x * 256 + threadIdx.x;
    if (i >= MN) return;
    float s = 0.f;
    for (int z = 0; z < KS; ++z) s += P[(size_t)z * MN + i];
    s = tanhf(s + bias[i % N]);
    if (EFMT == 1) {
        short h, l; splitf(s, h, l);
        oh[i] = (ushort)h; ol[i] = (ushort)l;
    } else {
        of[i] = s;
    }
}

// FC3: (128x2048) x (2048x62) f32 vector, K-split partials.
__global__ __launch_bounds__(64) void k_fc3_part(
    const float* __restrict__ A, const float* __restrict__ B,
    float* __restrict__ P, int K, int N, int KS)
{
    const int m = blockIdx.x, kz = blockIdx.y;
    const int n = threadIdx.x;
    const int kchunk = K / KS;
    if (n < N) {
        float acc = 0.f;
        const float* Am = A + (size_t)m * K;
        const int ke = (kz + 1) * kchunk;
        for (int k = kz * kchunk; k < ke; ++k)
            acc = fmaf(Am[k], B[(size_t)k * N + n], acc);
        P[((size_t)kz * 128 + m) * N + n] = acc;
    }
}

// Fused FC3 epilogue + DMP segment prep: one block, 256 threads.
// Phase A: p[i] = sum_z P[z][i] + bias (in LDS). Phase B: thread b<128 runs
// the per-batch serial cumsum (traj_start) from LDS.
__global__ __launch_bounds__(256) void k_fc3_fin(
    const float* __restrict__ P, const float* __restrict__ bias,
    const float* __restrict__ td, float* __restrict__ starts,
    float* __restrict__ sa, int* __restrict__ sidx)
{
    __shared__ float pp[128 * 62];
    const int t = threadIdx.x;
    for (int i = t; i < 128 * 62; i += 256) {
        float s = 0.f;
#pragma unroll
        for (int z = 0; z < 4; ++z) s += P[(size_t)z * 128 * 62 + i];
        pp[i] = s + bias[i % 62];
    }
    __syncthreads();
    if (t < 128) {
        const float* pb = &pp[t * 62];
        float cx = pb[0], cy = pb[1];
        for (int s = 0; s < 20; ++s) {
            float f  = pb[2 + 3 * s];
            float a0 = pb[3 + 3 * s];
            float a1 = pb[4 + 3 * s];
            int idx = (int)fminf(fmaxf(rintf(f), 0.f), 999.f);
            int bs = t * 20 + s;
            sidx[bs] = idx;
            sa[bs * 2 + 0] = a0;
            sa[bs * 2 + 1] = a1;
            starts[bs * 2 + 0] = cx;
            starts[bs * 2 + 1] = cy;
            cx += td[((size_t)idx * 200 + 199) * 2 + 0] * a0;
            cy += td[((size_t)idx * 200 + 199) * 2 + 1] * a1;
        }
    }
}

__global__ void k_traj_main(const float* __restrict__ td, const float* __restrict__ starts,
                            const float* __restrict__ sa, const int* __restrict__ sidx,
                            float* __restrict__ out)
{
    int bs = blockIdx.x;
    int idx = sidx[bs];
    float a0 = sa[bs * 2 + 0], a1 = sa[bs * 2 + 1];
    float s0 = starts[bs * 2 + 0], s1 = starts[bs * 2 + 1];
    const float* row = td + (size_t)idx * 400;
    float* o = out + (size_t)bs * 400;
    for (int e = threadIdx.x; e < 400; e += blockDim.x) {
        float v = row[e];
        o[e] = (e & 1) ? fmaf(v, a1, s1) : fmaf(v, a0, s0);
    }
}

// ---------------------------------------------------------------------------
template<int BPRE>
static void run_all(void* const* d_in, float* out, char* ws, hipStream_t stream)
{
    const float* x   = (const float*)d_in[0];
    const float* w1  = (const float*)d_in[1];
    const float* b1  = (const float*)d_in[2];
    const float* w2  = (const float*)d_in[3];
    const float* b2  = (const float*)d_in[4];
    const float* w3  = (const float*)d_in[5];
    const float* b3  = (const float*)d_in[6];
    const float* w4  = (const float*)d_in[7];
    const float* b4  = (const float*)d_in[8];
    const float* fw1 = (const float*)d_in[9];
    const float* fb1 = (const float*)d_in[10];
    const float* fw2 = (const float*)d_in[11];
    const float* fb2 = (const float*)d_in[12];
    const float* fw3 = (const float*)d_in[13];
    const float* fb3 = (const float*)d_in[14];
    const float* td  = (const float*)d_in[15];

    // ---- workspace layout (bytes), all activation tensors NHWC ----
    uint*   h1   = (uint*)ws;                          // [0, 78,675,968)
    uint*   h2   = (uint*)(ws + 78675968ull);          // 34,668,544
    uint*   h3   = (uint*)ws;                          // [0, 13,107,200)
    ushort* fw1h = (ushort*)(ws + 13107200ull);        // 33,554,432
    ushort* fw1l = (ushort*)(ws + 46661632ull);        // 33,554,432
    ushort* h4h  = (ushort*)(ws + 80216064ull);        // 2,097,152 (NCHW planes)
    ushort* h4l  = (ushort*)(ws + 82313216ull);        // 2,097,152
    ushort* fw2h = (ushort*)(ws + 84410368ull);        // 8,388,608
    ushort* fw2l = (ushort*)(ws + 92798976ull);        // 8,388,608
    float*  part = (float*)(ws + 101187584ull);        // 8,388,608
    ushort* a1h  = (ushort*)(ws + 109576192ull);       // 524,288
    ushort* a1l  = (ushort*)(ws + 110100480ull);       // 524,288
    float*  a2   = (float*)(ws + 110624768ull);        // 1,048,576
    float*  starts = (float*)(ws + 111705088ull);
    float*  sa   = (float*)(ws + 111725568ull);
    int*    sidx = (int*)(ws + 111746048ull);
    ushort* w2h = (ushort*)(ws + 113344512ull);
    ushort* w2l = (ushort*)(ws + 113491968ull);
    ushort* w3h = (ushort*)(ws + 113639424ull);
    ushort* w3l = (ushort*)(ws + 114229248ull);
    ushort* w4h = (ushort*)(ws + 114819072ull);
    ushort* w4l = (ushort*)(ws + 117178368ull);        // end 119,537,664

    if (BPRE) {   // permuted split: [n][ci*9+r] -> [n][r*CIN+ci]
        k_wsplit_perm<<<(73728 + 255) / 256, 256, 0, stream>>>(w2, w2h, w2l, 64, 73728);
        k_wsplit_perm<<<(294912 + 255) / 256, 256, 0, stream>>>(w3, w3h, w3l, 128, 294912);
        k_wsplit_perm<<<(1179648 + 255) / 256, 256, 0, stream>>>(w4, w4h, w4l, 256, 1179648);
    }

    // conv1: 3->64, 100 -> pool 49 (direct, NHWC out)
    k_conv_pool_relu<3, 100, 49, 16, 256, 3, 64>
        <<<dim3(10, 4, 128), 256, 0, stream>>>(x, w1, b1, h1);

    // conv2: 64->128, K=576, pooled 23x23=529 (17 tiles of 32 pooled), N=128
    k_gemm4<0, BPRE, 0, 6, 576, 576, 128, 49, 23, 23, 128, 17, 128, 1>
        <<<dim3(17 * 128, 1), 256, 0, stream>>>(
            h1, nullptr, BPRE ? (const void*)w2h : (const void*)w2,
            BPRE ? (const void*)w2l : nullptr, b2, h2, nullptr);
    // conv3: 128->256, K=1152, pooled 10x10=100 (4 tiles of 32 pooled), N=256
    k_gemm4<0, BPRE, 0, 7, 1152, 1152, 256, 23, 10, 10, 256, 4, 128, 1>
        <<<dim3(4 * 128, 2), 256, 0, stream>>>(
            h2, nullptr, BPRE ? (const void*)w3h : (const void*)w3,
            BPRE ? (const void*)w3l : nullptr, b3, h3, nullptr);

    if (BPRE) {   // h1/h2-head dead; build FC weight planes
        k_wsplitT<<<dim3(2048 / 32, 8192 / 32), 256, 0, stream>>>(fw1, fw1h, fw1l, 8192, 2048);
        k_wsplitT<<<dim3(2048 / 32, 2048 / 32), 256, 0, stream>>>(fw2, fw2h, fw2l, 2048, 2048);
    }

    // conv4: 256->512, K=2304, pooled 4x4 (IPB=2 images per 128-row tile),
    // N=512 -> h4 NCHW planes
    k_gemm4<0, BPRE, 1, 8, 2304, 2304, 512, 10, 4, 4, 512, 1, 128, 2>
        <<<dim3(64, 4), 256, 0, stream>>>(
            h3, nullptr, BPRE ? (const void*)w4h : (const void*)w4,
            BPRE ? (const void*)w4l : nullptr, b4, h4h, h4l);

    // FC1: (128x8192)x(8192x2048), MT=64, KS=8 partials + tanh -> a1 planes
    k_gemm4<1, BPRE, 2, 0, 8192, 1024, 2048, 1, 1, 1, 1, 1, 64, 1>
        <<<dim3(2, 16, 8), 256, 0, stream>>>(
            h4h, h4l, BPRE ? (const void*)fw1h : (const void*)fw1,
            BPRE ? (const void*)fw1l : nullptr, nullptr, part, nullptr);
    k_fc_epi2<1><<<(128 * 2048 + 255) / 256, 256, 0, stream>>>(
        part, fb1, a1h, a1l, nullptr, 128 * 2048, 2048, 8);
    // FC2: (128x2048)x(2048x2048), MT=64, KS=8 partials + tanh -> a2 f32
    k_gemm4<1, BPRE, 2, 0, 2048, 256, 2048, 1, 1, 1, 1, 1, 64, 1>
        <<<dim3(2, 16, 8), 256, 0, stream>>>(
            a1h, a1l, BPRE ? (const void*)fw2h : (const void*)fw2,
            BPRE ? (const void*)fw2l : nullptr, nullptr, part, nullptr);
    k_fc_epi2<2><<<(128 * 2048 + 255) / 256, 256, 0, stream>>>(
        part, fb2, nullptr, nullptr, a2, 128 * 2048, 2048, 8);

    // FC3 (f32 vector) + fused epilogue/segment-prep + trajectory composition
    k_fc3_part<<<dim3(128, 4), 64, 0, stream>>>(a2, fw3, part, 2048, 62, 4);
    k_fc3_fin<<<1, 256, 0, stream>>>(part, fb3, td, starts, sa, sidx);
    k_traj_main<<<2560, 256, 0, stream>>>(td, starts, sa, sidx, out);
}

extern "C" void kernel_launch(void* const* d_in, const int* in_sizes, int n_in,
                              void* d_out, int out_size, void* d_ws, size_t ws_size,
                              hipStream_t stream)
{
    (void)in_sizes; (void)n_in; (void)out_size;
    if (ws_size >= 119537664ull)
        run_all<1>(d_in, (float*)d_out, (char*)d_ws, stream);
    else
        run_all<0>(d_in, (float*)d_out, (char*)d_ws, stream);
}

// Round 9
// 938.611 us; speedup vs baseline: 1.0771x; 1.0303x over previous
//
#include <hip/hip_runtime.h>
#include <hip/hip_bf16.h>

typedef __attribute__((ext_vector_type(8))) short s8v;
typedef __attribute__((ext_vector_type(4))) float f4v;
typedef unsigned short ushort;
typedef unsigned int uint;

union V8 { s8v v; short s[8]; };

__device__ __forceinline__ short f2bf(float v){
    union { __hip_bfloat16 b; short u; } x;
    x.b = __float2bfloat16(v);
    return x.u;
}
__device__ __forceinline__ float bf2f(short u){
    union { short u; __hip_bfloat16 b; } x;
    x.u = u;
    return __bfloat162float(x.b);
}
__device__ __forceinline__ void splitf(float v, short& h, short& l){
    h = f2bf(v);
    l = f2bf(v - bf2f(h));
}
__device__ __forceinline__ uint packsplit(float v){
    short h, l; splitf(v, h, l);
    return (uint)(ushort)h | ((uint)(ushort)l << 16);
}

// ---------------------------------------------------------------------------
// conv1 (CIN=3): direct conv + pool + ReLU -> NHWC interleaved-split u32.
// ---------------------------------------------------------------------------
template<int CIN, int HIN, int PH, int OCB, int SPT, int CICH, int COUT>
__global__ __launch_bounds__(SPT) void k_conv_pool_relu(
    const float* __restrict__ in, const float* __restrict__ w,
    const float* __restrict__ bias, uint* __restrict__ out)
{
    constexpr int WIN   = HIN;
    constexpr int PW    = PH;
    constexpr int WSTR  = CICH * 9 + 1;

    __shared__ float wsh[OCB * WSTR];

    const int b   = blockIdx.z;
    const int oc0 = blockIdx.y * OCB;
    const int t   = threadIdx.x;
    const int sp  = blockIdx.x * SPT + t;
    const bool active = sp < PH * PW;
    const int py = active ? (sp / PW) : 0;
    const int px = active ? (sp % PW) : 0;

    float acc[OCB][4];
#pragma unroll
    for (int j = 0; j < OCB; ++j)
        acc[j][0] = acc[j][1] = acc[j][2] = acc[j][3] = 0.f;

    const float* inb = in + (size_t)b * CIN * HIN * WIN;

    for (int c0 = 0; c0 < CIN; c0 += CICH) {
        __syncthreads();
        for (int i = t; i < OCB * CICH * 9; i += SPT) {
            int j = i / (CICH * 9);
            int r = i - j * (CICH * 9);
            wsh[j * WSTR + r] = w[((size_t)(oc0 + j) * CIN + c0) * 9 + r];
        }
        __syncthreads();

        for (int ci = 0; ci < CICH; ++ci) {
            const float* inc = inb + (size_t)(c0 + ci) * HIN * WIN
                             + (2 * py) * WIN + 2 * px;
            float patch[4][4];
#pragma unroll
            for (int r = 0; r < 4; ++r)
#pragma unroll
                for (int c = 0; c < 4; ++c)
                    patch[r][c] = inc[r * WIN + c];

#pragma unroll
            for (int j = 0; j < OCB; ++j) {
                const float* wp = &wsh[j * WSTR + ci * 9];
#pragma unroll
                for (int kh = 0; kh < 3; ++kh)
#pragma unroll
                    for (int kw = 0; kw < 3; ++kw) {
                        float wv = wp[kh * 3 + kw];
                        acc[j][0] = fmaf(patch[kh][kw],         wv, acc[j][0]);
                        acc[j][1] = fmaf(patch[kh][kw + 1],     wv, acc[j][1]);
                        acc[j][2] = fmaf(patch[kh + 1][kw],     wv, acc[j][2]);
                        acc[j][3] = fmaf(patch[kh + 1][kw + 1], wv, acc[j][3]);
                    }
            }
        }
    }

    if (active) {
        uint tmp[OCB];
#pragma unroll
        for (int j = 0; j < OCB; ++j) {
            float m = fmaxf(fmaxf(acc[j][0], acc[j][1]),
                            fmaxf(acc[j][2], acc[j][3]));
            m = fmaxf(m + bias[oc0 + j], 0.f);
            tmp[j] = packsplit(m);
        }
        // NHWC: [b][p][oc]
        uint* ob = out + ((size_t)b * PH * PW + sp) * COUT + oc0;
#pragma unroll
        for (int q = 0; q < OCB / 4; ++q)
            ((uint4*)ob)[q] = ((const uint4*)tmp)[q];
    }
}

// ---------------------------------------------------------------------------
// Conv weight split WITH K-permutation: w[n][ci*9+r] -> planes [n][r*CIN+ci].
// ---------------------------------------------------------------------------
__global__ void k_wsplit_perm(const float* __restrict__ w, ushort* __restrict__ oh,
                              ushort* __restrict__ ol, int CIN, int total)
{
    int i = blockIdx.x * 256 + threadIdx.x;
    if (i < total) {
        int K = CIN * 9;
        int n = i / K;
        int rem = i - n * K;
        int ci = rem / 9;
        int r = rem - 9 * ci;
        short h, l; splitf(w[i], h, l);
        size_t o = (size_t)n * K + r * CIN + ci;
        oh[o] = (ushort)h; ol[o] = (ushort)l;
    }
}

// Transpose+split: f32 [K][N] -> hi/lo ushort planes [n][k]. 32x32 tiles.
__global__ __launch_bounds__(256) void k_wsplitT(
    const float* __restrict__ B, ushort* __restrict__ oh, ushort* __restrict__ ol,
    int K, int N)
{
    __shared__ float tl[32][33];
    const int n0 = blockIdx.x * 32, k0 = blockIdx.y * 32;
    const int r = threadIdx.x >> 5, c = threadIdx.x & 31;
#pragma unroll
    for (int it = 0; it < 4; ++it) {
        int row = r + it * 8;
        tl[row][c] = B[(size_t)(k0 + row) * N + n0 + c];
    }
    __syncthreads();
#pragma unroll
    for (int it = 0; it < 4; ++it) {
        int a = r + it * 8;
        float v = tl[c][a];
        short h, l; splitf(v, h, l);
        size_t o = (size_t)(n0 + a) * K + k0 + c;
        oh[o] = (ushort)h; ol[o] = (ushort)l;
    }
}

// ---------------------------------------------------------------------------
// Split-bf16 MFMA GEMM v11: R2 structure + IPB + XCD chunk-swizzle (MODE 0).
// MT=128: tile 128x128, 4 waves, wave = 64x64 (4x4 subtiles), 48 MFMA/K-step.
// MT=64 : tile 64x128, wave = 32x64 (2x4 subtiles).
// Rule (R8): keep grid >= 512 blocks (>=2 blocks/CU) — TLP hides the
// 2-barrier drain; 1 block/CU exposes it (conv4 MT=128 regression).
// MODE 0: implicit-GEMM conv, NHWC interleaved-split u32 A; in-register
//   2x2 maxpool + bias + ReLU epilogue. EPI 0: NHWC u32; EPI 1: NCHW planes.
// MODE 1: FC partial (grid.z K-split), A/B hi-lo ushort planes, f32 partials.
// ---------------------------------------------------------------------------
template<int MODE, int BPRE, int EPI, int LOG2CIN, int K, int KCH, int N,
         int HIN, int PPH, int PPW, int COUT, int TPI, int MT, int IPB>
__global__ __launch_bounds__(256) void k_gemm4(
    const void* __restrict__ A0, const void* __restrict__ A1,
    const void* __restrict__ B0, const void* __restrict__ B1,
    const float* __restrict__ bias, void* __restrict__ O0, void* __restrict__ O1)
{
    constexpr int CIN  = 1 << LOG2CIN;
    constexpr int HH   = HIN * HIN;
    constexpr int PP   = PPH * PPW;
    constexpr int WM   = MT / 32;     // M-subtiles per wave (2 or 4)
    constexpr int AOPT = MT / 64;     // A-octets staged per thread (1 or 2)
    constexpr int OSTEP = 256 / MT;   // octet stride between q's (4 or 2)

    __shared__ short Ah[MT][40], Al[MT][40], Bh[128][40], Bl[128][40];

    const int t    = threadIdx.x;
    const int lane = t & 63;
    const int wave = t >> 6;
    const int n0   = blockIdx.y * 128;
    const int sArow = t & (MT - 1), sAo0 = t / MT;
    const int sBrow = t & 127, sBo = t >> 7;

    const uint*   ArI = nullptr;   // NHWC base at (img, y0, x0, 0)
    const ushort* Ahg = nullptr;
    const ushort* Alg = nullptr;
    int b = 0, ptile = 0, kbeg = 0, kend = K;

    if (MODE == 0) {
        // XCD chunk-swizzle (T1): grid.x % 8 == 0 for all conv dispatches.
        // XCD x gets original blocks [x*cpx, (x+1)*cpx) -> image locality per L2.
        const int cpx = (int)gridDim.x >> 3;
        const int bid = (int)blockIdx.x;
        const int swz = (bid & 7) * cpx + (bid >> 3);
        int bb = swz / TPI;
        ptile = swz - bb * TPI;
        b = bb * IPB;                      // base image of this block
        int pl = ptile * (MT / 4) + (sArow >> 2);
        int quad = sArow & 3;
        int isub = 0, pll = pl;
        if (IPB > 1) {
            if (pl < IPB * PP) { isub = pl / PP; pll = pl - isub * PP; }
            else { isub = 0; pll = 0; }
        }
        int py = 0, px = 0;
        if (pll < PP) { py = pll / PPW; px = pll - py * PPW; }
        ArI = (const uint*)A0
            + ((size_t)(b + isub) * HH + (size_t)(2 * py + (quad >> 1)) * HIN
               + (2 * px + (quad & 1))) * CIN;
    } else {
        int arow = blockIdx.x * MT + sArow;
        Ahg = (const ushort*)A0 + (size_t)arow * K;
        Alg = (const ushort*)A1 + (size_t)arow * K;
        kbeg = blockIdx.z * KCH;
        kend = kbeg + KCH;
    }

    // ---- prefetch helpers ----
    auto pfA = [&](int kkx, V8* ha, V8* la) {
#pragma unroll
        for (int q = 0; q < AOPT; ++q) {
            const int kb = kkx + (sAo0 + q * OSTEP) * 8;
            if (MODE == 0) {
                const int r  = kb >> LOG2CIN;       // wave-uniform
                const int cb = kb & (CIN - 1);      // wave-uniform, multiple of 8
                const int rh = (r * 11) >> 5;       // r/3 for r<9
                const int rw = r - 3 * rh;
                const uint* g = ArI + (rh * HIN + rw) * CIN + cb;  // 32B contiguous
                uint4 v0 = *(const uint4*)g;
                uint4 v1 = *(const uint4*)(g + 4);
                uint vv[8] = {v0.x, v0.y, v0.z, v0.w, v1.x, v1.y, v1.z, v1.w};
#pragma unroll
                for (int j = 0; j < 8; ++j) {
                    ha[q].s[j] = (short)(vv[j] & 0xffffu);
                    la[q].s[j] = (short)(vv[j] >> 16);
                }
            } else {
                ha[q].v = *(const s8v*)(Ahg + kb);
                la[q].v = *(const s8v*)(Alg + kb);
            }
        }
    };
    auto pfB = [&](int kkx, V8* hb, V8* lb) {
#pragma unroll
        for (int q = 0; q < 2; ++q) {
            const int o = sBo + 2 * q;
            const int kb = kkx + o * 8;
            if (BPRE) {
                hb[q].v = *(const s8v*)((const ushort*)B0 + (size_t)(n0 + sBrow) * K + kb);
                lb[q].v = *(const s8v*)((const ushort*)B1 + (size_t)(n0 + sBrow) * K + kb);
            } else if (MODE == 0) {
                // fallback: permuted gather from f32 w[n][ci*9+r], stride 9
                const int r  = kb >> LOG2CIN;
                const int cb = kb & (CIN - 1);
                const float* bp = (const float*)B0
                    + (size_t)(n0 + sBrow) * K + (size_t)cb * 9 + r;
#pragma unroll
                for (int j = 0; j < 8; ++j)
                    splitf(bp[9 * j], hb[q].s[j], lb[q].s[j]);
            } else {
                const float* bp = (const float*)B0 + (size_t)kb * N + n0 + sBrow;
#pragma unroll
                for (int j = 0; j < 8; ++j)
                    splitf(bp[(size_t)j * N], hb[q].s[j], lb[q].s[j]);
            }
        }
    };

    f4v acc[WM][4];
    const f4v z4 = {0.f, 0.f, 0.f, 0.f};
#pragma unroll
    for (int i = 0; i < WM; ++i)
#pragma unroll
        for (int j = 0; j < 4; ++j) acc[i][j] = z4;

    V8 pAh[AOPT], pAl[AOPT], pBh[2], pBl[2];
    pfA(kbeg, pAh, pAl);
    pfB(kbeg, pBh, pBl);

    for (int kk = kbeg; kk < kend; kk += 32) {
        __syncthreads();                       // prev iter's frag reads done
#pragma unroll
        for (int q = 0; q < AOPT; ++q) {
            const int o = sAo0 + q * OSTEP;
            *(s8v*)&Ah[sArow][o * 8] = pAh[q].v;
            *(s8v*)&Al[sArow][o * 8] = pAl[q].v;
        }
#pragma unroll
        for (int q = 0; q < 2; ++q) {
            const int o = sBo + 2 * q;
            *(s8v*)&Bh[sBrow][o * 8] = pBh[q].v;
            *(s8v*)&Bl[sBrow][o * 8] = pBl[q].v;
        }
        if (kk + 32 < kend) {                  // overlap next loads with MFMA
            pfA(kk + 32, pAh, pAl);
            pfB(kk + 32, pBh, pBl);
        }
        __syncthreads();                       // LDS tile visible

        const int fm = lane & 15;
        const int fk = (lane >> 4) * 8;
        s8v a_h[WM], a_l[WM], b_h[4], b_l[4];
#pragma unroll
        for (int i = 0; i < WM; ++i) {
            a_h[i] = *(const s8v*)&Ah[(wave & 1) * (MT / 2) + i * 16 + fm][fk];
            a_l[i] = *(const s8v*)&Al[(wave & 1) * (MT / 2) + i * 16 + fm][fk];
        }
#pragma unroll
        for (int j = 0; j < 4; ++j) {
            b_h[j] = *(const s8v*)&Bh[(wave >> 1) * 64 + j * 16 + fm][fk];
            b_l[j] = *(const s8v*)&Bl[(wave >> 1) * 64 + j * 16 + fm][fk];
        }
#define MF(a_, b_, c_) c_ = __builtin_amdgcn_mfma_f32_16x16x32_bf16(a_, b_, c_, 0, 0, 0)
#pragma unroll
        for (int i = 0; i < WM; ++i)
#pragma unroll
            for (int j = 0; j < 4; ++j) {
                MF(a_h[i], b_h[j], acc[i][j]);
                MF(a_h[i], b_l[j], acc[i][j]);
                MF(a_l[i], b_h[j], acc[i][j]);
            }
#undef MF
    }

    if (MODE == 0) {
#pragma unroll
        for (int i = 0; i < WM; ++i)
#pragma unroll
            for (int j = 0; j < 4; ++j) {
                int p  = ptile * (MT / 4) + (wave & 1) * (MT / 8) + i * 4 + (lane >> 4);
                int oc = n0 + (wave >> 1) * 64 + j * 16 + (lane & 15);
                if (p < IPB * PP) {
                    int isub = (IPB > 1) ? (p / PP) : 0;
                    int pp   = p - isub * PP;
                    int img  = b + isub;
                    f4v v = acc[i][j];
                    float m = fmaxf(fmaxf(v.x, v.y), fmaxf(v.z, v.w));
                    m = fmaxf(m + bias[oc], 0.f);
                    if (EPI == 0) {
                        // NHWC interleaved u32 (consecutive oc per lane-group)
                        ((uint*)O0)[((size_t)img * PP + pp) * COUT + oc] = packsplit(m);
                    } else {
                        // NCHW hi/lo planes (FC1 A layout)
                        size_t o = (size_t)(img * COUT + oc) * PP + pp;
                        short h, l; splitf(m, h, l);
                        ((ushort*)O0)[o] = (ushort)h;
                        ((ushort*)O1)[o] = (ushort)l;
                    }
                }
            }
    } else {
        float* P = (float*)O0 + (size_t)blockIdx.z * 128 * N;
#pragma unroll
        for (int i = 0; i < WM; ++i)
#pragma unroll
            for (int j = 0; j < 4; ++j) {
                int n = n0 + (wave >> 1) * 64 + j * 16 + (lane & 15);
                int mb = blockIdx.x * MT + (wave & 1) * (MT / 2) + i * 16 + (lane >> 4) * 4;
                f4v v = acc[i][j];
                P[(size_t)(mb + 0) * N + n] = v.x;
                P[(size_t)(mb + 1) * N + n] = v.y;
                P[(size_t)(mb + 2) * N + n] = v.z;
                P[(size_t)(mb + 3) * N + n] = v.w;
            }
    }
}

// FC partial-sum epilogue: sum KS partials + bias + tanh; EFMT 1: split planes,
// EFMT 2: f32.
template<int EFMT>
__global__ void k_fc_epi2(const float* __restrict__ P, const float* __restrict__ bias,
                          ushort* __restrict__ oh, ushort* __restrict__ ol,
                          float* __restrict__ of, int MN, int N, int KS)
{
    int i = blockIdx.x * 256 + threadIdx.x;
    if (i >= MN) return;
    float s = 0.f;
    for (int z = 0; z < KS; ++z) s += P[(size_t)z * MN + i];
    s = tanhf(s + bias[i % N]);
    if (EFMT == 1) {
        short h, l; splitf(s, h, l);
        oh[i] = (ushort)h; ol[i] = (ushort)l;
    } else {
        of[i] = s;
    }
}

// FC3: (128x2048) x (2048x62) f32 vector, K-split partials.
__global__ __launch_bounds__(64) void k_fc3_part(
    const float* __restrict__ A, const float* __restrict__ B,
    float* __restrict__ P, int K, int N, int KS)
{
    const int m = blockIdx.x, kz = blockIdx.y;
    const int n = threadIdx.x;
    const int kchunk = K / KS;
    if (n < N) {
        float acc = 0.f;
        const float* Am = A + (size_t)m * K;
        const int ke = (kz + 1) * kchunk;
        for (int k = kz * kchunk; k < ke; ++k)
            acc = fmaf(Am[k], B[(size_t)k * N + n], acc);
        P[((size_t)kz * 128 + m) * N + n] = acc;
    }
}

// Fused FC3 epilogue + DMP segment prep: one block, 256 threads.
__global__ __launch_bounds__(256) void k_fc3_fin(
    const float* __restrict__ P, const float* __restrict__ bias,
    const float* __restrict__ td, float* __restrict__ starts,
    float* __restrict__ sa, int* __restrict__ sidx)
{
    __shared__ float pp[128 * 62];
    const int t = threadIdx.x;
    for (int i = t; i < 128 * 62; i += 256) {
        float s = 0.f;
#pragma unroll
        for (int z = 0; z < 4; ++z) s += P[(size_t)z * 128 * 62 + i];
        pp[i] = s + bias[i % 62];
    }
    __syncthreads();
    if (t < 128) {
        const float* pb = &pp[t * 62];
        float cx = pb[0], cy = pb[1];
        for (int s = 0; s < 20; ++s) {
            float f  = pb[2 + 3 * s];
            float a0 = pb[3 + 3 * s];
            float a1 = pb[4 + 3 * s];
            int idx = (int)fminf(fmaxf(rintf(f), 0.f), 999.f);
            int bs = t * 20 + s;
            sidx[bs] = idx;
            sa[bs * 2 + 0] = a0;
            sa[bs * 2 + 1] = a1;
            starts[bs * 2 + 0] = cx;
            starts[bs * 2 + 1] = cy;
            cx += td[((size_t)idx * 200 + 199) * 2 + 0] * a0;
            cy += td[((size_t)idx * 200 + 199) * 2 + 1] * a1;
        }
    }
}

__global__ void k_traj_main(const float* __restrict__ td, const float* __restrict__ starts,
                            const float* __restrict__ sa, const int* __restrict__ sidx,
                            float* __restrict__ out)
{
    int bs = blockIdx.x;
    int idx = sidx[bs];
    float a0 = sa[bs * 2 + 0], a1 = sa[bs * 2 + 1];
    float s0 = starts[bs * 2 + 0], s1 = starts[bs * 2 + 1];
    const float* row = td + (size_t)idx * 400;
    float* o = out + (size_t)bs * 400;
    for (int e = threadIdx.x; e < 400; e += blockDim.x) {
        float v = row[e];
        o[e] = (e & 1) ? fmaf(v, a1, s1) : fmaf(v, a0, s0);
    }
}

// ---------------------------------------------------------------------------
template<int BPRE>
static void run_all(void* const* d_in, float* out, char* ws, hipStream_t stream)
{
    const float* x   = (const float*)d_in[0];
    const float* w1  = (const float*)d_in[1];
    const float* b1  = (const float*)d_in[2];
    const float* w2  = (const float*)d_in[3];
    const float* b2  = (const float*)d_in[4];
    const float* w3  = (const float*)d_in[5];
    const float* b3  = (const float*)d_in[6];
    const float* w4  = (const float*)d_in[7];
    const float* b4  = (const float*)d_in[8];
    const float* fw1 = (const float*)d_in[9];
    const float* fb1 = (const float*)d_in[10];
    const float* fw2 = (const float*)d_in[11];
    const float* fb2 = (const float*)d_in[12];
    const float* fw3 = (const float*)d_in[13];
    const float* fb3 = (const float*)d_in[14];
    const float* td  = (const float*)d_in[15];

    // ---- workspace layout (bytes), all activation tensors NHWC ----
    uint*   h1   = (uint*)ws;                          // [0, 78,675,968)
    uint*   h2   = (uint*)(ws + 78675968ull);          // 34,668,544
    uint*   h3   = (uint*)ws;                          // [0, 13,107,200)
    ushort* fw1h = (ushort*)(ws + 13107200ull);        // 33,554,432
    ushort* fw1l = (ushort*)(ws + 46661632ull);        // 33,554,432
    ushort* h4h  = (ushort*)(ws + 80216064ull);        // 2,097,152 (NCHW planes)
    ushort* h4l  = (ushort*)(ws + 82313216ull);        // 2,097,152
    ushort* fw2h = (ushort*)(ws + 84410368ull);        // 8,388,608
    ushort* fw2l = (ushort*)(ws + 92798976ull);        // 8,388,608
    float*  part = (float*)(ws + 101187584ull);        // 8,388,608
    ushort* a1h  = (ushort*)(ws + 109576192ull);       // 524,288
    ushort* a1l  = (ushort*)(ws + 110100480ull);       // 524,288
    float*  a2   = (float*)(ws + 110624768ull);        // 1,048,576
    float*  starts = (float*)(ws + 111705088ull);
    float*  sa   = (float*)(ws + 111725568ull);
    int*    sidx = (int*)(ws + 111746048ull);
    ushort* w2h = (ushort*)(ws + 113344512ull);
    ushort* w2l = (ushort*)(ws + 113491968ull);
    ushort* w3h = (ushort*)(ws + 113639424ull);
    ushort* w3l = (ushort*)(ws + 114229248ull);
    ushort* w4h = (ushort*)(ws + 114819072ull);
    ushort* w4l = (ushort*)(ws + 117178368ull);        // end 119,537,664

    if (BPRE) {   // permuted split: [n][ci*9+r] -> [n][r*CIN+ci]
        k_wsplit_perm<<<(73728 + 255) / 256, 256, 0, stream>>>(w2, w2h, w2l, 64, 73728);
        k_wsplit_perm<<<(294912 + 255) / 256, 256, 0, stream>>>(w3, w3h, w3l, 128, 294912);
        k_wsplit_perm<<<(1179648 + 255) / 256, 256, 0, stream>>>(w4, w4h, w4l, 256, 1179648);
    }

    // conv1: 3->64, 100 -> pool 49 (direct, NHWC out)
    k_conv_pool_relu<3, 100, 49, 16, 256, 3, 64>
        <<<dim3(10, 4, 128), 256, 0, stream>>>(x, w1, b1, h1);

    // conv2: 64->128, K=576, pooled 23x23=529 (17 tiles of 32 pooled), N=128
    k_gemm4<0, BPRE, 0, 6, 576, 576, 128, 49, 23, 23, 128, 17, 128, 1>
        <<<dim3(17 * 128, 1), 256, 0, stream>>>(
            h1, nullptr, BPRE ? (const void*)w2h : (const void*)w2,
            BPRE ? (const void*)w2l : nullptr, b2, h2, nullptr);
    // conv3: 128->256, K=1152, pooled 10x10=100 (4 tiles of 32 pooled), N=256
    k_gemm4<0, BPRE, 0, 7, 1152, 1152, 256, 23, 10, 10, 256, 4, 128, 1>
        <<<dim3(4 * 128, 2), 256, 0, stream>>>(
            h2, nullptr, BPRE ? (const void*)w3h : (const void*)w3,
            BPRE ? (const void*)w3l : nullptr, b3, h3, nullptr);

    if (BPRE) {   // h1/h2-head dead; build FC weight planes
        k_wsplitT<<<dim3(2048 / 32, 8192 / 32), 256, 0, stream>>>(fw1, fw1h, fw1l, 8192, 2048);
        k_wsplitT<<<dim3(2048 / 32, 2048 / 32), 256, 0, stream>>>(fw2, fw2h, fw2l, 2048, 2048);
    }

    // conv4: 256->512, K=2304, pooled 4x4 (1 tile/img), N=512 -> h4 NCHW planes
    // MT=64, 512 blocks (>=2 blocks/CU rule — R8 post-mortem)
    k_gemm4<0, BPRE, 1, 8, 2304, 2304, 512, 10, 4, 4, 512, 1, 64, 1>
        <<<dim3(128, 4), 256, 0, stream>>>(
            h3, nullptr, BPRE ? (const void*)w4h : (const void*)w4,
            BPRE ? (const void*)w4l : nullptr, b4, h4h, h4l);

    // FC1: (128x8192)x(8192x2048), MT=64, KS=8 partials + tanh -> a1 planes
    k_gemm4<1, BPRE, 2, 0, 8192, 1024, 2048, 1, 1, 1, 1, 1, 64, 1>
        <<<dim3(2, 16, 8), 256, 0, stream>>>(
            h4h, h4l, BPRE ? (const void*)fw1h : (const void*)fw1,
            BPRE ? (const void*)fw1l : nullptr, nullptr, part, nullptr);
    k_fc_epi2<1><<<(128 * 2048 + 255) / 256, 256, 0, stream>>>(
        part, fb1, a1h, a1l, nullptr, 128 * 2048, 2048, 8);
    // FC2: (128x2048)x(2048x2048), MT=64, KS=8 partials + tanh -> a2 f32
    k_gemm4<1, BPRE, 2, 0, 2048, 256, 2048, 1, 1, 1, 1, 1, 64, 1>
        <<<dim3(2, 16, 8), 256, 0, stream>>>(
            a1h, a1l, BPRE ? (const void*)fw2h : (const void*)fw2,
            BPRE ? (const void*)fw2l : nullptr, nullptr, part, nullptr);
    k_fc_epi2<2><<<(128 * 2048 + 255) / 256, 256, 0, stream>>>(
        part, fb2, nullptr, nullptr, a2, 128 * 2048, 2048, 8);

    // FC3 (f32 vector) + fused epilogue/segment-prep + trajectory composition
    k_fc3_part<<<dim3(128, 4), 64, 0, stream>>>(a2, fw3, part, 2048, 62, 4);
    k_fc3_fin<<<1, 256, 0, stream>>>(part, fb3, td, starts, sa, sidx);
    k_traj_main<<<2560, 256, 0, stream>>>(td, starts, sa, sidx, out);
}

extern "C" void kernel_launch(void* const* d_in, const int* in_sizes, int n_in,
                              void* d_out, int out_size, void* d_ws, size_t ws_size,
                              hipStream_t stream)
{
    (void)in_sizes; (void)n_in; (void)out_size;
    if (ws_size >= 119537664ull)
        run_all<1>(d_in, (float*)d_out, (char*)d_ws, stream);
    else
        run_all<0>(d_in, (float*)d_out, (char*)d_ws, stream);
}